// Round 1
// baseline (1023.389 us; speedup 1.0000x reference)
//
#include <hip/hip_runtime.h>
#include <hip/hip_bf16.h>
#include <math.h>

// Problem constants
#define S_LEN 1024
#define HIDN  1024
#define NHEAD 16
#define HDIM  64
#define BATCH 4
#define MTOT  (BATCH * S_LEN)   // 4096

// ---------------------------------------------------------------------------
// Generic f32 GEMM: C[M,N] = A[M,K] @ B[K,N] (+ bias), optional batched PV mode.
// BM=128, BN=64, BK=16, 256 threads, 8x4 per-thread tile.
// pvmode=1: blockIdx.z = b*16+h; A += z*S*S (attn matrices), B/C offset into
// per-head 64-wide column slice of [B,S,HID] tensors.
// ---------------------------------------------------------------------------
__global__ __launch_bounds__(256) void gemm_f32(
    const float* __restrict__ A, const float* __restrict__ B,
    const float* __restrict__ bias, float* __restrict__ C,
    int M, int N, int K, int lda, int ldb, int ldc, int pvmode)
{
    __shared__ float As[16][132];   // k-major, padded (4kk+8ty banks -> broadcast)
    __shared__ float Bs[16][64];

    const int t  = threadIdx.x;
    const int bm = blockIdx.y * 128;
    const int bn = blockIdx.x * 64;

    if (pvmode) {
        const int z = blockIdx.z;
        A += (size_t)z * (size_t)S_LEN * (size_t)S_LEN;
        const size_t off = (size_t)(z >> 4) * S_LEN * HIDN + (size_t)(z & 15) * HDIM;
        B += off;
        C += off;
    }

    const int ty = t >> 4;          // 0..15 -> rows ty*8..ty*8+7
    const int tx = t & 15;          // cols tx*4..tx*4+3

    float acc[8][4];
#pragma unroll
    for (int i = 0; i < 8; ++i)
#pragma unroll
        for (int j = 0; j < 4; ++j) acc[i][j] = 0.f;

    for (int k0 = 0; k0 < K; k0 += 16) {
        // stage A tile 128x16 (transpose-scatter, 2-way conflicts only)
#pragma unroll
        for (int i = 0; i < 2; ++i) {
            const int idx = t + i * 256;      // float4 index 0..511
            const int row = idx >> 2;         // 0..127
            const int kk4 = (idx & 3) << 2;   // 0,4,8,12
            const float4 a4 = *reinterpret_cast<const float4*>(
                &A[(size_t)(bm + row) * lda + k0 + kk4]);
            As[kk4 + 0][row] = a4.x;
            As[kk4 + 1][row] = a4.y;
            As[kk4 + 2][row] = a4.z;
            As[kk4 + 3][row] = a4.w;
        }
        // stage B tile 16x64 (direct float4)
        {
            const int kk = t >> 4;
            const int c4 = (t & 15) << 2;
            *reinterpret_cast<float4*>(&Bs[kk][c4]) =
                *reinterpret_cast<const float4*>(&B[(size_t)(k0 + kk) * ldb + bn + c4]);
        }
        __syncthreads();

#pragma unroll
        for (int kk = 0; kk < 16; ++kk) {
            const float4 a0 = *reinterpret_cast<const float4*>(&As[kk][ty * 8]);
            const float4 a1 = *reinterpret_cast<const float4*>(&As[kk][ty * 8 + 4]);
            const float4 b0 = *reinterpret_cast<const float4*>(&Bs[kk][tx * 4]);
            const float av[8] = {a0.x, a0.y, a0.z, a0.w, a1.x, a1.y, a1.z, a1.w};
            const float bv[4] = {b0.x, b0.y, b0.z, b0.w};
#pragma unroll
            for (int i = 0; i < 8; ++i)
#pragma unroll
                for (int j = 0; j < 4; ++j)
                    acc[i][j] = fmaf(av[i], bv[j], acc[i][j]);
        }
        __syncthreads();
    }

    float4 bb = make_float4(0.f, 0.f, 0.f, 0.f);
    if (bias) bb = *reinterpret_cast<const float4*>(&bias[bn + tx * 4]);
#pragma unroll
    for (int i = 0; i < 8; ++i) {
        const int row = bm + ty * 8 + i;
        float4 o;
        o.x = acc[i][0] + bb.x;
        o.y = acc[i][1] + bb.y;
        o.z = acc[i][2] + bb.z;
        o.w = acc[i][3] + bb.w;
        *reinterpret_cast<float4*>(&C[(size_t)row * ldc + bn + tx * 4]) = o;
    }
}

// ---------------------------------------------------------------------------
// alpha = sigmoid(query @ Wus + bus)   [MTOT,16]
// block = 256 threads handles 16 rows; Wus (64 KB) staged in LDS.
// ---------------------------------------------------------------------------
__global__ __launch_bounds__(256) void alpha_kernel(
    const float* __restrict__ X, const float* __restrict__ Wus,
    const float* __restrict__ bus, float* __restrict__ alpha)
{
    __shared__ float Ws[1024 * 16];
    const int t = threadIdx.x;
#pragma unroll
    for (int i = 0; i < 16; ++i) {
        const int idx = t + i * 256;          // float4 idx, 4096 total
        *reinterpret_cast<float4*>(&Ws[idx * 4]) =
            *reinterpret_cast<const float4*>(&Wus[idx * 4]);
    }
    __syncthreads();

    const int r = t >> 4, c = t & 15;
    const size_t row = (size_t)blockIdx.x * 16 + r;
    const float* x = &X[row * 1024];
    float acc = 0.f;
    for (int kk = 0; kk < 1024; kk += 4) {
        const float4 xv = *reinterpret_cast<const float4*>(&x[kk]);
        acc = fmaf(xv.x, Ws[(kk + 0) * 16 + c], acc);
        acc = fmaf(xv.y, Ws[(kk + 1) * 16 + c], acc);
        acc = fmaf(xv.z, Ws[(kk + 2) * 16 + c], acc);
        acc = fmaf(xv.w, Ws[(kk + 3) * 16 + c], acc);
    }
    acc += bus[c];
    alpha[row * 16 + c] = 1.f / (1.f + expf(-acc));
}

// ---------------------------------------------------------------------------
// Gaussian-window parameters per (b,h,s):
//   tp = tanh(p_row); p_i = tp.Wup+bup; z_i = tp.Wud+bud
//   cen = S*sigmoid(p_i); win = S*sigmoid(z_i); c0 = alpha * 2 / win^2
// ---------------------------------------------------------------------------
__global__ __launch_bounds__(256) void posparam_kernel(
    const float* __restrict__ p, const float* __restrict__ alpha,
    const float* __restrict__ Wup, const float* __restrict__ bup,
    const float* __restrict__ Wud, const float* __restrict__ bud,
    float* __restrict__ cen, float* __restrict__ c0)
{
    __shared__ float wu[64], wd[64];
    const int t = threadIdx.x;
    if (t < 64) { wu[t] = Wup[t]; wd[t] = Wud[t]; }
    __syncthreads();

    const int tid = blockIdx.x * 256 + t;
    const int b = tid >> 14;
    const int h = (tid >> 10) & 15;
    const int s = tid & 1023;

    const float* pr = &p[((size_t)(b * 1024 + s)) * 1024 + h * 64];
    float ap = 0.f, az = 0.f;
#pragma unroll
    for (int d = 0; d < 64; d += 4) {
        const float4 pv = *reinterpret_cast<const float4*>(&pr[d]);
        const float t0 = tanhf(pv.x), t1 = tanhf(pv.y);
        const float t2 = tanhf(pv.z), t3 = tanhf(pv.w);
        ap += t0 * wu[d] + t1 * wu[d + 1] + t2 * wu[d + 2] + t3 * wu[d + 3];
        az += t0 * wd[d] + t1 * wd[d + 1] + t2 * wd[d + 2] + t3 * wd[d + 3];
    }
    ap += bup[0];
    az += bud[0];
    const float cenv = 1024.f / (1.f + expf(-ap));
    const float win  = 1024.f / (1.f + expf(-az));
    const float al   = alpha[(size_t)(b * 1024 + s) * 16 + h];
    const int oi = (b * 16 + h) * 1024 + s;
    cen[oi] = cenv;
    c0[oi]  = al * 2.f / (win * win);
}

// ---------------------------------------------------------------------------
// scores[b,h,i,j] = (qh_i . kh_j) * 0.125 - c0[b,h,i]*(j - cen[b,h,i])^2
// NT GEMM, K=64 single shot. BM=BN=128, 256 threads, 8x8 per-thread tile.
// Writes raw (pre-softmax) scores into the attn output region.
// ---------------------------------------------------------------------------
__global__ __launch_bounds__(256) void score_kernel(
    const float* __restrict__ q, const float* __restrict__ k,
    const float* __restrict__ cen, const float* __restrict__ c0,
    float* __restrict__ attn)
{
    __shared__ float Qs[64][132];   // [d][row]
    __shared__ float Ks[64][132];   // [d][col]

    const int t  = threadIdx.x;
    const int z  = blockIdx.z;                 // b*16 + h
    const int b  = z >> 4, h = z & 15;
    const int i0 = blockIdx.y * 128;
    const int j0 = blockIdx.x * 128;
    const size_t base = (size_t)b * S_LEN * HIDN + (size_t)h * HDIM;

#pragma unroll
    for (int i = 0; i < 8; ++i) {
        const int idx = t + i * 256;          // 0..2047
        const int r   = idx >> 4;             // 0..127
        const int d4  = (idx & 15) << 2;      // 0..60
        const float4 a4 = *reinterpret_cast<const float4*>(
            &q[base + (size_t)(i0 + r) * HIDN + d4]);
        Qs[d4 + 0][r] = a4.x; Qs[d4 + 1][r] = a4.y;
        Qs[d4 + 2][r] = a4.z; Qs[d4 + 3][r] = a4.w;
        const float4 b4 = *reinterpret_cast<const float4*>(
            &k[base + (size_t)(j0 + r) * HIDN + d4]);
        Ks[d4 + 0][r] = b4.x; Ks[d4 + 1][r] = b4.y;
        Ks[d4 + 2][r] = b4.z; Ks[d4 + 3][r] = b4.w;
    }
    __syncthreads();

    const int ty = t >> 4, tx = t & 15;
    const int r0 = ty * 8, cc0 = tx * 8;

    float acc[8][8];
#pragma unroll
    for (int i = 0; i < 8; ++i)
#pragma unroll
        for (int j = 0; j < 8; ++j) acc[i][j] = 0.f;

    for (int d = 0; d < 64; ++d) {
        const float4 a0 = *reinterpret_cast<const float4*>(&Qs[d][r0]);
        const float4 a1 = *reinterpret_cast<const float4*>(&Qs[d][r0 + 4]);
        const float4 b0 = *reinterpret_cast<const float4*>(&Ks[d][cc0]);
        const float4 b1 = *reinterpret_cast<const float4*>(&Ks[d][cc0 + 4]);
        const float av[8] = {a0.x, a0.y, a0.z, a0.w, a1.x, a1.y, a1.z, a1.w};
        const float bv[8] = {b0.x, b0.y, b0.z, b0.w, b1.x, b1.y, b1.z, b1.w};
#pragma unroll
        for (int i = 0; i < 8; ++i)
#pragma unroll
            for (int j = 0; j < 8; ++j)
                acc[i][j] = fmaf(av[i], bv[j], acc[i][j]);
    }

    float cenv[8], c0v[8];
#pragma unroll
    for (int i = 0; i < 8; ++i) {
        const int row = i0 + r0 + i;
        cenv[i] = cen[(size_t)z * S_LEN + row];
        c0v[i]  = c0[(size_t)z * S_LEN + row];
    }

#pragma unroll
    for (int i = 0; i < 8; ++i) {
        const size_t rowoff = (size_t)z * S_LEN * S_LEN +
                              (size_t)(i0 + r0 + i) * S_LEN + j0 + cc0;
        float4 o0, o1;
        float* po = (float*)&o0;
#pragma unroll
        for (int j = 0; j < 8; ++j) {
            const float jf = (float)(j0 + cc0 + j);
            const float dd = jf - cenv[i];
            const float s  = acc[i][j] * 0.125f - c0v[i] * dd * dd;
            if (j < 4) ((float*)&o0)[j] = s; else ((float*)&o1)[j - 4] = s;
        }
        (void)po;
        *reinterpret_cast<float4*>(&attn[rowoff])     = o0;
        *reinterpret_cast<float4*>(&attn[rowoff + 4]) = o1;
    }
}

// ---------------------------------------------------------------------------
// Row softmax in-place over the attn region. One block (256 thr) per row.
// ---------------------------------------------------------------------------
__global__ __launch_bounds__(256) void softmax_kernel(float* __restrict__ attn)
{
    __shared__ float red[8];
    const size_t row = blockIdx.x;
    float* p = attn + row * 1024;
    const int t = threadIdx.x;

    const float4 v = *reinterpret_cast<const float4*>(&p[t * 4]);
    float m = fmaxf(fmaxf(v.x, v.y), fmaxf(v.z, v.w));
#pragma unroll
    for (int off = 1; off < 64; off <<= 1) m = fmaxf(m, __shfl_xor(m, off));
    if ((t & 63) == 0) red[t >> 6] = m;
    __syncthreads();
    m = fmaxf(fmaxf(red[0], red[1]), fmaxf(red[2], red[3]));

    const float e0 = expf(v.x - m), e1 = expf(v.y - m);
    const float e2 = expf(v.z - m), e3 = expf(v.w - m);
    float s = e0 + e1 + e2 + e3;
#pragma unroll
    for (int off = 1; off < 64; off <<= 1) s += __shfl_xor(s, off);
    if ((t & 63) == 0) red[4 + (t >> 6)] = s;
    __syncthreads();
    s = red[4] + red[5] + red[6] + red[7];

    const float r = 1.f / s;
    float4 o;
    o.x = e0 * r; o.y = e1 * r; o.z = e2 * r; o.w = e3 * r;
    *reinterpret_cast<float4*>(&p[t * 4]) = o;
}

// ---------------------------------------------------------------------------
extern "C" void kernel_launch(void* const* d_in, const int* in_sizes, int n_in,
                              void* d_out, int out_size, void* d_ws, size_t ws_size,
                              hipStream_t stream)
{
    const float* query = (const float*)d_in[0];
    const float* key_  = (const float*)d_in[1];
    const float* value = (const float*)d_in[2];
    const float* Wq  = (const float*)d_in[3];
    const float* bq  = (const float*)d_in[4];
    const float* Wk  = (const float*)d_in[5];
    const float* bk  = (const float*)d_in[6];
    const float* Wv  = (const float*)d_in[7];
    const float* bv  = (const float*)d_in[8];
    const float* Wp  = (const float*)d_in[9];
    const float* bp  = (const float*)d_in[10];
    const float* Wup = (const float*)d_in[11];
    const float* bup = (const float*)d_in[12];
    const float* Wud = (const float*)d_in[13];
    const float* bud = (const float*)d_in[14];
    const float* Wus = (const float*)d_in[15];
    const float* bus = (const float*)d_in[16];
    const float* Wo  = (const float*)d_in[17];
    const float* bo  = (const float*)d_in[18];

    float* x_out = (float*)d_out;                                   // [4096,1024]
    float* attn  = (float*)d_out + (size_t)MTOT * HIDN;             // [4,16,1024,1024]

    float* q_ws     = (float*)d_ws;
    float* k_ws     = q_ws + (size_t)MTOT * HIDN;
    float* v_ws     = k_ws + (size_t)MTOT * HIDN;
    float* o_ws     = v_ws + (size_t)MTOT * HIDN;   // p (temp), then attn-out
    float* alpha_ws = o_ws + (size_t)MTOT * HIDN;
    float* cen_ws   = alpha_ws + (size_t)MTOT * NHEAD;
    float* c0_ws    = cen_ws + (size_t)BATCH * NHEAD * S_LEN;

    const dim3 blk(256);
    const dim3 gproj(HIDN / 64, MTOT / 128, 1);

    // 1-3: q/k/v projections
    gemm_f32<<<gproj, blk, 0, stream>>>(query, Wq, bq, q_ws,
        MTOT, HIDN, HIDN, HIDN, HIDN, HIDN, 0);
    gemm_f32<<<gproj, blk, 0, stream>>>(key_, Wk, bk, k_ws,
        MTOT, HIDN, HIDN, HIDN, HIDN, HIDN, 0);
    gemm_f32<<<gproj, blk, 0, stream>>>(value, Wv, bv, v_ws,
        MTOT, HIDN, HIDN, HIDN, HIDN, HIDN, 0);
    // 4: p = q @ Wp + bp  (temporarily into o_ws)
    gemm_f32<<<gproj, blk, 0, stream>>>(q_ws, Wp, bp, o_ws,
        MTOT, HIDN, HIDN, HIDN, HIDN, HIDN, 0);
    // 5: alpha
    alpha_kernel<<<dim3(MTOT / 16), blk, 0, stream>>>(query, Wus, bus, alpha_ws);
    // 6: Gaussian-window params
    posparam_kernel<<<dim3((BATCH * NHEAD * S_LEN) / 256), blk, 0, stream>>>(
        o_ws, alpha_ws, Wup, bup, Wud, bud, cen_ws, c0_ws);
    // 7: biased scores -> attn region
    score_kernel<<<dim3(S_LEN / 128, S_LEN / 128, BATCH * NHEAD), blk, 0, stream>>>(
        q_ws, k_ws, cen_ws, c0_ws, attn);
    // 8: softmax in place
    softmax_kernel<<<dim3(BATCH * NHEAD * S_LEN), blk, 0, stream>>>(attn);
    // 9: out = attn @ vh (batched over 64 (b,h)), into o_ws [B,S,HID]
    gemm_f32<<<dim3(1, S_LEN / 128, BATCH * NHEAD), blk, 0, stream>>>(
        attn, v_ws, nullptr, o_ws,
        S_LEN, HDIM, S_LEN, S_LEN, HIDN, HIDN, 1);
    // 10: x = out @ Wo + bo
    gemm_f32<<<gproj, blk, 0, stream>>>(o_ws, Wo, bo, x_out,
        MTOT, HIDN, HIDN, HIDN, HIDN, HIDN, 0);
}

// Round 2
// 663.755 us; speedup vs baseline: 1.5418x; 1.5418x over previous
//
#include <hip/hip_runtime.h>
#include <hip/hip_bf16.h>
#include <math.h>

// Problem constants
#define S_LEN 1024
#define HIDN  1024
#define NHEAD 16
#define HDIM  64
#define BATCH 4
#define MTOT  (BATCH * S_LEN)   // 4096

typedef __attribute__((ext_vector_type(8))) short          bf16v8;
typedef __attribute__((ext_vector_type(8))) unsigned short u16v8;
typedef __attribute__((ext_vector_type(4))) float          f32v4;

// ---------------------------------------------------------------------------
// bf16 hi/lo split helpers (RNE)
// ---------------------------------------------------------------------------
__device__ __forceinline__ unsigned short f2bf_rne(float x) {
    unsigned int u = __float_as_uint(x);
    unsigned int r = (u + 0x7fffu + ((u >> 16) & 1u)) >> 16;
    return (unsigned short)r;
}
__device__ __forceinline__ float bf2f(unsigned short h) {
    return __uint_as_float(((unsigned int)h) << 16);
}
__device__ __forceinline__ void split2(float x, unsigned short& h, unsigned short& l) {
    h = f2bf_rne(x);
    l = f2bf_rne(x - bf2f(h));
}

// ---------------------------------------------------------------------------
// split_a: row-major f32 [M][1024] -> Ah, Al bf16 (same layout). 8 elems/thread.
// ---------------------------------------------------------------------------
__global__ __launch_bounds__(256) void split_a(
    const float* __restrict__ X, unsigned short* __restrict__ H,
    unsigned short* __restrict__ L)
{
    const int i = blockIdx.x * 256 + threadIdx.x;     // handles 8 elements
    const float4 x0 = ((const float4*)X)[2 * i];
    const float4 x1 = ((const float4*)X)[2 * i + 1];
    float xs[8] = {x0.x, x0.y, x0.z, x0.w, x1.x, x1.y, x1.z, x1.w};
    u16v8 h, l;
#pragma unroll
    for (int j = 0; j < 8; ++j) {
        unsigned short hh, ll;
        split2(xs[j], hh, ll);
        h[j] = hh; l[j] = ll;
    }
    ((u16v8*)H)[i] = h;
    ((u16v8*)L)[i] = l;
}

// ---------------------------------------------------------------------------
// split_w: W f32 [K=1024][N=1024] -> transposed Ht, Lt bf16 [N][K] (k-contig).
// 64x64 tiles via LDS.
// ---------------------------------------------------------------------------
__global__ __launch_bounds__(256) void split_w(
    const float* __restrict__ W, unsigned short* __restrict__ H,
    unsigned short* __restrict__ L)
{
    __shared__ float T[64][65];
    const int t  = threadIdx.x;
    const int k0 = blockIdx.y * 64;
    const int n0 = blockIdx.x * 64;

    const int r = t >> 4;           // 0..15
    const int c = (t & 15) * 4;
#pragma unroll
    for (int i = 0; i < 4; ++i) {
        const int rr = r + i * 16;
        const float4 v = *(const float4*)&W[(size_t)(k0 + rr) * 1024 + n0 + c];
        T[rr][c + 0] = v.x; T[rr][c + 1] = v.y;
        T[rr][c + 2] = v.z; T[rr][c + 3] = v.w;
    }
    __syncthreads();

    const int n  = t >> 2;          // 0..63
    const int ko = (t & 3) * 16;
    u16v8 h0, h1, l0, l1;
#pragma unroll
    for (int kk = 0; kk < 8; ++kk) {
        unsigned short hh, ll;
        split2(T[ko + kk][n], hh, ll);
        h0[kk] = hh; l0[kk] = ll;
    }
#pragma unroll
    for (int kk = 0; kk < 8; ++kk) {
        unsigned short hh, ll;
        split2(T[ko + 8 + kk][n], hh, ll);
        h1[kk] = hh; l1[kk] = ll;
    }
    unsigned short* Hp = &H[(size_t)(n0 + n) * 1024 + k0 + ko];
    unsigned short* Lp = &L[(size_t)(n0 + n) * 1024 + k0 + ko];
    *(u16v8*)(Hp)     = h0;
    *(u16v8*)(Hp + 8) = h1;
    *(u16v8*)(Lp)     = l0;
    *(u16v8*)(Lp + 8) = l1;
}

// ---------------------------------------------------------------------------
// bf16x3 MFMA GEMM: C[M][1024] = A[M][1024] @ B(1024x1024, given transposed
// hi/lo bf16 [n][k]) + bias.  BM=BN=128, BK=32, 256 threads (4 waves, 2x2),
// each wave 64x64 out via 4x4 frags of mfma_f32_16x16x32_bf16.
// ---------------------------------------------------------------------------
__global__ __launch_bounds__(256) void gemm_bf16x3(
    const unsigned short* __restrict__ Ah, const unsigned short* __restrict__ Al,
    const unsigned short* __restrict__ Bh, const unsigned short* __restrict__ Bl,
    const float* __restrict__ bias, float* __restrict__ C)
{
    __shared__ short Ash[128][40];
    __shared__ short Asl[128][40];
    __shared__ short Bsh[128][40];
    __shared__ short Bsl[128][40];

    const int t    = threadIdx.x;
    const int bm   = blockIdx.y * 128;
    const int bn   = blockIdx.x * 128;
    const int lane = t & 63;
    const int w    = t >> 6;
    const int wr   = w >> 1;        // 0..1
    const int wc   = w & 1;         // 0..1
    const int fr   = lane & 15;
    const int fq   = lane >> 4;     // 0..3
    const int ks   = fq * 8;

    f32v4 zero = {0.f, 0.f, 0.f, 0.f};
    f32v4 acc[4][4];
#pragma unroll
    for (int i = 0; i < 4; ++i)
#pragma unroll
        for (int j = 0; j < 4; ++j) acc[i][j] = zero;

    // staging: thread -> row sr (0..127), k-offset sc (0 or 16)
    const int sr = t >> 1;
    const int sc = (t & 1) * 16;
    const unsigned short* pAh = &Ah[(size_t)(bm + sr) * 1024 + sc];
    const unsigned short* pAl = &Al[(size_t)(bm + sr) * 1024 + sc];
    const unsigned short* pBh = &Bh[(size_t)(bn + sr) * 1024 + sc];
    const unsigned short* pBl = &Bl[(size_t)(bn + sr) * 1024 + sc];

    u16v8 rah0, rah1, ral0, ral1, rbh0, rbh1, rbl0, rbl1;
    auto LOAD = [&](int k0) {
        rah0 = *(const u16v8*)(pAh + k0);
        rah1 = *(const u16v8*)(pAh + k0 + 8);
        ral0 = *(const u16v8*)(pAl + k0);
        ral1 = *(const u16v8*)(pAl + k0 + 8);
        rbh0 = *(const u16v8*)(pBh + k0);
        rbh1 = *(const u16v8*)(pBh + k0 + 8);
        rbl0 = *(const u16v8*)(pBl + k0);
        rbl1 = *(const u16v8*)(pBl + k0 + 8);
    };

    LOAD(0);
    for (int k0 = 0; k0 < 1024; k0 += 32) {
        __syncthreads();            // previous iteration's readers done
        *(u16v8*)&Ash[sr][sc]     = rah0;
        *(u16v8*)&Ash[sr][sc + 8] = rah1;
        *(u16v8*)&Asl[sr][sc]     = ral0;
        *(u16v8*)&Asl[sr][sc + 8] = ral1;
        *(u16v8*)&Bsh[sr][sc]     = rbh0;
        *(u16v8*)&Bsh[sr][sc + 8] = rbh1;
        *(u16v8*)&Bsl[sr][sc]     = rbl0;
        *(u16v8*)&Bsl[sr][sc + 8] = rbl1;
        __syncthreads();

        if (k0 + 32 < 1024) LOAD(k0 + 32);   // overlap next loads with compute

        bf16v8 fah[4], fal[4], fbh[4], fbl[4];
#pragma unroll
        for (int i = 0; i < 4; ++i) {
            fah[i] = *(const bf16v8*)&Ash[wr * 64 + i * 16 + fr][ks];
            fal[i] = *(const bf16v8*)&Asl[wr * 64 + i * 16 + fr][ks];
            fbh[i] = *(const bf16v8*)&Bsh[wc * 64 + i * 16 + fr][ks];
            fbl[i] = *(const bf16v8*)&Bsl[wc * 64 + i * 16 + fr][ks];
        }
#pragma unroll
        for (int i = 0; i < 4; ++i)
#pragma unroll
            for (int j = 0; j < 4; ++j) {
                acc[i][j] = __builtin_amdgcn_mfma_f32_16x16x32_bf16(
                    fah[i], fbh[j], acc[i][j], 0, 0, 0);
                acc[i][j] = __builtin_amdgcn_mfma_f32_16x16x32_bf16(
                    fah[i], fbl[j], acc[i][j], 0, 0, 0);
                acc[i][j] = __builtin_amdgcn_mfma_f32_16x16x32_bf16(
                    fal[i], fbh[j], acc[i][j], 0, 0, 0);
            }
    }

    // epilogue: D col = lane&15, row = (lane>>4)*4 + reg
#pragma unroll
    for (int j = 0; j < 4; ++j) {
        const int col = bn + wc * 64 + j * 16 + fr;
        const float bb = bias[col];
#pragma unroll
        for (int i = 0; i < 4; ++i) {
            const int row0 = bm + wr * 64 + i * 16 + fq * 4;
            const f32v4 cv = acc[i][j];
#pragma unroll
            for (int r = 0; r < 4; ++r)
                C[(size_t)(row0 + r) * 1024 + col] = cv[r] + bb;
        }
    }
}

// ---------------------------------------------------------------------------
// f32 GEMM kept for PV: out = attn @ vh (batched over z = b*16+h)
// ---------------------------------------------------------------------------
__global__ __launch_bounds__(256) void gemm_f32(
    const float* __restrict__ A, const float* __restrict__ B,
    const float* __restrict__ bias, float* __restrict__ C,
    int M, int N, int K, int lda, int ldb, int ldc, int pvmode)
{
    __shared__ float As[16][132];
    __shared__ float Bs[16][64];

    const int t  = threadIdx.x;
    const int bm = blockIdx.y * 128;
    const int bn = blockIdx.x * 64;

    if (pvmode) {
        const int z = blockIdx.z;
        A += (size_t)z * (size_t)S_LEN * (size_t)S_LEN;
        const size_t off = (size_t)(z >> 4) * S_LEN * HIDN + (size_t)(z & 15) * HDIM;
        B += off;
        C += off;
    }

    const int ty = t >> 4;
    const int tx = t & 15;

    float acc[8][4];
#pragma unroll
    for (int i = 0; i < 8; ++i)
#pragma unroll
        for (int j = 0; j < 4; ++j) acc[i][j] = 0.f;

    for (int k0 = 0; k0 < K; k0 += 16) {
#pragma unroll
        for (int i = 0; i < 2; ++i) {
            const int idx = t + i * 256;
            const int row = idx >> 2;
            const int kk4 = (idx & 3) << 2;
            const float4 a4 = *reinterpret_cast<const float4*>(
                &A[(size_t)(bm + row) * lda + k0 + kk4]);
            As[kk4 + 0][row] = a4.x;
            As[kk4 + 1][row] = a4.y;
            As[kk4 + 2][row] = a4.z;
            As[kk4 + 3][row] = a4.w;
        }
        {
            const int kk = t >> 4;
            const int c4 = (t & 15) << 2;
            *reinterpret_cast<float4*>(&Bs[kk][c4]) =
                *reinterpret_cast<const float4*>(&B[(size_t)(k0 + kk) * ldb + bn + c4]);
        }
        __syncthreads();

#pragma unroll
        for (int kk = 0; kk < 16; ++kk) {
            const float4 a0 = *reinterpret_cast<const float4*>(&As[kk][ty * 8]);
            const float4 a1 = *reinterpret_cast<const float4*>(&As[kk][ty * 8 + 4]);
            const float4 b0 = *reinterpret_cast<const float4*>(&Bs[kk][tx * 4]);
            const float av[8] = {a0.x, a0.y, a0.z, a0.w, a1.x, a1.y, a1.z, a1.w};
            const float bv[4] = {b0.x, b0.y, b0.z, b0.w};
#pragma unroll
            for (int i = 0; i < 8; ++i)
#pragma unroll
                for (int j = 0; j < 4; ++j)
                    acc[i][j] = fmaf(av[i], bv[j], acc[i][j]);
        }
        __syncthreads();
    }

    float4 bb = make_float4(0.f, 0.f, 0.f, 0.f);
    if (bias) bb = *reinterpret_cast<const float4*>(&bias[bn + tx * 4]);
#pragma unroll
    for (int i = 0; i < 8; ++i) {
        const int row = bm + ty * 8 + i;
        float4 o;
        o.x = acc[i][0] + bb.x;
        o.y = acc[i][1] + bb.y;
        o.z = acc[i][2] + bb.z;
        o.w = acc[i][3] + bb.w;
        *reinterpret_cast<float4*>(&C[(size_t)row * ldc + bn + tx * 4]) = o;
    }
}

// ---------------------------------------------------------------------------
// alpha = sigmoid(query @ Wus + bus)   [MTOT,16]
// ---------------------------------------------------------------------------
__global__ __launch_bounds__(256) void alpha_kernel(
    const float* __restrict__ X, const float* __restrict__ Wus,
    const float* __restrict__ bus, float* __restrict__ alpha)
{
    __shared__ float Ws[1024 * 16];
    const int t = threadIdx.x;
#pragma unroll
    for (int i = 0; i < 16; ++i) {
        const int idx = t + i * 256;
        *reinterpret_cast<float4*>(&Ws[idx * 4]) =
            *reinterpret_cast<const float4*>(&Wus[idx * 4]);
    }
    __syncthreads();

    const int r = t >> 4, c = t & 15;
    const size_t row = (size_t)blockIdx.x * 16 + r;
    const float* x = &X[row * 1024];
    float acc = 0.f;
    for (int kk = 0; kk < 1024; kk += 4) {
        const float4 xv = *reinterpret_cast<const float4*>(&x[kk]);
        acc = fmaf(xv.x, Ws[(kk + 0) * 16 + c], acc);
        acc = fmaf(xv.y, Ws[(kk + 1) * 16 + c], acc);
        acc = fmaf(xv.z, Ws[(kk + 2) * 16 + c], acc);
        acc = fmaf(xv.w, Ws[(kk + 3) * 16 + c], acc);
    }
    acc += bus[c];
    alpha[row * 16 + c] = 1.f / (1.f + expf(-acc));
}

// ---------------------------------------------------------------------------
// Gaussian-window parameters per (b,h,s)
// ---------------------------------------------------------------------------
__global__ __launch_bounds__(256) void posparam_kernel(
    const float* __restrict__ p, const float* __restrict__ alpha,
    const float* __restrict__ Wup, const float* __restrict__ bup,
    const float* __restrict__ Wud, const float* __restrict__ bud,
    float* __restrict__ cen, float* __restrict__ c0)
{
    __shared__ float wu[64], wd[64];
    const int t = threadIdx.x;
    if (t < 64) { wu[t] = Wup[t]; wd[t] = Wud[t]; }
    __syncthreads();

    const int tid = blockIdx.x * 256 + t;
    const int b = tid >> 14;
    const int h = (tid >> 10) & 15;
    const int s = tid & 1023;

    const float* pr = &p[((size_t)(b * 1024 + s)) * 1024 + h * 64];
    float ap = 0.f, az = 0.f;
#pragma unroll
    for (int d = 0; d < 64; d += 4) {
        const float4 pv = *reinterpret_cast<const float4*>(&pr[d]);
        const float t0 = tanhf(pv.x), t1 = tanhf(pv.y);
        const float t2 = tanhf(pv.z), t3 = tanhf(pv.w);
        ap += t0 * wu[d] + t1 * wu[d + 1] + t2 * wu[d + 2] + t3 * wu[d + 3];
        az += t0 * wd[d] + t1 * wd[d + 1] + t2 * wd[d + 2] + t3 * wd[d + 3];
    }
    ap += bup[0];
    az += bud[0];
    const float cenv = 1024.f / (1.f + expf(-ap));
    const float win  = 1024.f / (1.f + expf(-az));
    const float al   = alpha[(size_t)(b * 1024 + s) * 16 + h];
    const int oi = (b * 16 + h) * 1024 + s;
    cen[oi] = cenv;
    c0[oi]  = al * 2.f / (win * win);
}

// ---------------------------------------------------------------------------
// scores -> attn region (pre-softmax)
// ---------------------------------------------------------------------------
__global__ __launch_bounds__(256) void score_kernel(
    const float* __restrict__ q, const float* __restrict__ k,
    const float* __restrict__ cen, const float* __restrict__ c0,
    float* __restrict__ attn)
{
    __shared__ float Qs[64][132];
    __shared__ float Ks[64][132];

    const int t  = threadIdx.x;
    const int z  = blockIdx.z;
    const int b  = z >> 4, h = z & 15;
    const int i0 = blockIdx.y * 128;
    const int j0 = blockIdx.x * 128;
    const size_t base = (size_t)b * S_LEN * HIDN + (size_t)h * HDIM;

#pragma unroll
    for (int i = 0; i < 8; ++i) {
        const int idx = t + i * 256;
        const int r   = idx >> 4;
        const int d4  = (idx & 15) << 2;
        const float4 a4 = *reinterpret_cast<const float4*>(
            &q[base + (size_t)(i0 + r) * HIDN + d4]);
        Qs[d4 + 0][r] = a4.x; Qs[d4 + 1][r] = a4.y;
        Qs[d4 + 2][r] = a4.z; Qs[d4 + 3][r] = a4.w;
        const float4 b4 = *reinterpret_cast<const float4*>(
            &k[base + (size_t)(j0 + r) * HIDN + d4]);
        Ks[d4 + 0][r] = b4.x; Ks[d4 + 1][r] = b4.y;
        Ks[d4 + 2][r] = b4.z; Ks[d4 + 3][r] = b4.w;
    }
    __syncthreads();

    const int ty = t >> 4, tx = t & 15;
    const int r0 = ty * 8, cc0 = tx * 8;

    float acc[8][8];
#pragma unroll
    for (int i = 0; i < 8; ++i)
#pragma unroll
        for (int j = 0; j < 8; ++j) acc[i][j] = 0.f;

    for (int d = 0; d < 64; ++d) {
        const float4 a0 = *reinterpret_cast<const float4*>(&Qs[d][r0]);
        const float4 a1 = *reinterpret_cast<const float4*>(&Qs[d][r0 + 4]);
        const float4 b0 = *reinterpret_cast<const float4*>(&Ks[d][cc0]);
        const float4 b1 = *reinterpret_cast<const float4*>(&Ks[d][cc0 + 4]);
        const float av[8] = {a0.x, a0.y, a0.z, a0.w, a1.x, a1.y, a1.z, a1.w};
        const float bv[8] = {b0.x, b0.y, b0.z, b0.w, b1.x, b1.y, b1.z, b1.w};
#pragma unroll
        for (int i = 0; i < 8; ++i)
#pragma unroll
            for (int j = 0; j < 8; ++j)
                acc[i][j] = fmaf(av[i], bv[j], acc[i][j]);
    }

    float cenv[8], c0v[8];
#pragma unroll
    for (int i = 0; i < 8; ++i) {
        const int row = i0 + r0 + i;
        cenv[i] = cen[(size_t)z * S_LEN + row];
        c0v[i]  = c0[(size_t)z * S_LEN + row];
    }

#pragma unroll
    for (int i = 0; i < 8; ++i) {
        const size_t rowoff = (size_t)z * S_LEN * S_LEN +
                              (size_t)(i0 + r0 + i) * S_LEN + j0 + cc0;
        float4 o0, o1;
#pragma unroll
        for (int j = 0; j < 8; ++j) {
            const float jf = (float)(j0 + cc0 + j);
            const float dd = jf - cenv[i];
            const float s  = acc[i][j] * 0.125f - c0v[i] * dd * dd;
            if (j < 4) ((float*)&o0)[j] = s; else ((float*)&o1)[j - 4] = s;
        }
        *reinterpret_cast<float4*>(&attn[rowoff])     = o0;
        *reinterpret_cast<float4*>(&attn[rowoff + 4]) = o1;
    }
}

// ---------------------------------------------------------------------------
// Row softmax in-place
// ---------------------------------------------------------------------------
__global__ __launch_bounds__(256) void softmax_kernel(float* __restrict__ attn)
{
    __shared__ float red[8];
    const size_t row = blockIdx.x;
    float* p = attn + row * 1024;
    const int t = threadIdx.x;

    const float4 v = *reinterpret_cast<const float4*>(&p[t * 4]);
    float m = fmaxf(fmaxf(v.x, v.y), fmaxf(v.z, v.w));
#pragma unroll
    for (int off = 1; off < 64; off <<= 1) m = fmaxf(m, __shfl_xor(m, off));
    if ((t & 63) == 0) red[t >> 6] = m;
    __syncthreads();
    m = fmaxf(fmaxf(red[0], red[1]), fmaxf(red[2], red[3]));

    const float e0 = expf(v.x - m), e1 = expf(v.y - m);
    const float e2 = expf(v.z - m), e3 = expf(v.w - m);
    float s = e0 + e1 + e2 + e3;
#pragma unroll
    for (int off = 1; off < 64; off <<= 1) s += __shfl_xor(s, off);
    if ((t & 63) == 0) red[4 + (t >> 6)] = s;
    __syncthreads();
    s = red[4] + red[5] + red[6] + red[7];

    const float r = 1.f / s;
    float4 o;
    o.x = e0 * r; o.y = e1 * r; o.z = e2 * r; o.w = e3 * r;
    *reinterpret_cast<float4*>(&p[t * 4]) = o;
}

// ---------------------------------------------------------------------------
extern "C" void kernel_launch(void* const* d_in, const int* in_sizes, int n_in,
                              void* d_out, int out_size, void* d_ws, size_t ws_size,
                              hipStream_t stream)
{
    const float* query = (const float*)d_in[0];
    const float* key_  = (const float*)d_in[1];
    const float* value = (const float*)d_in[2];
    const float* Wq  = (const float*)d_in[3];
    const float* bq  = (const float*)d_in[4];
    const float* Wk  = (const float*)d_in[5];
    const float* bk  = (const float*)d_in[6];
    const float* Wv  = (const float*)d_in[7];
    const float* bv  = (const float*)d_in[8];
    const float* Wp  = (const float*)d_in[9];
    const float* bp  = (const float*)d_in[10];
    const float* Wup = (const float*)d_in[11];
    const float* bup = (const float*)d_in[12];
    const float* Wud = (const float*)d_in[13];
    const float* bud = (const float*)d_in[14];
    const float* Wus = (const float*)d_in[15];
    const float* bus = (const float*)d_in[16];
    const float* Wo  = (const float*)d_in[17];
    const float* bo  = (const float*)d_in[18];

    float* x_out = (float*)d_out;                         // [4096,1024]
    float* attn  = x_out + (size_t)MTOT * HIDN;           // [4,16,1024,1024]

    float* q_ws     = (float*)d_ws;
    float* k_ws     = q_ws + (size_t)MTOT * HIDN;
    float* v_ws     = k_ws + (size_t)MTOT * HIDN;
    float* o_ws     = v_ws + (size_t)MTOT * HIDN;   // p (temp), then attn-out
    float* alpha_ws = o_ws + (size_t)MTOT * HIDN;
    float* cen_ws   = alpha_ws + (size_t)MTOT * NHEAD;
    float* c0_ws    = cen_ws + (size_t)BATCH * NHEAD * S_LEN;

    // bf16 split scratch living in the attn region (overwritten by score later)
    unsigned short* ah_s = (unsigned short*)attn;                     // 8 MB
    unsigned short* al_s = ah_s + (size_t)MTOT * HIDN;                // 8 MB
    unsigned short* wh_s = al_s + (size_t)MTOT * HIDN;                // 2 MB
    unsigned short* wl_s = wh_s + (size_t)HIDN * HIDN;                // 2 MB

    // final-stage split scratch (q_ws/k_ws are dead by then)
    unsigned short* oh_s  = (unsigned short*)q_ws;
    unsigned short* ol_s  = oh_s + (size_t)MTOT * HIDN;
    unsigned short* w2h_s = (unsigned short*)k_ws;
    unsigned short* w2l_s = w2h_s + (size_t)HIDN * HIDN;

    const dim3 blk(256);
    const dim3 gsplit_a(MTOT * HIDN / 8 / 256);
    const dim3 gsplit_w(16, 16);
    const dim3 ggemm(HIDN / 128, MTOT / 128);

    // q = query @ Wq + bq
    split_w<<<gsplit_w, blk, 0, stream>>>(Wq, wh_s, wl_s);
    split_a<<<gsplit_a, blk, 0, stream>>>(query, ah_s, al_s);
    gemm_bf16x3<<<ggemm, blk, 0, stream>>>(ah_s, al_s, wh_s, wl_s, bq, q_ws);
    // k
    split_w<<<gsplit_w, blk, 0, stream>>>(Wk, wh_s, wl_s);
    split_a<<<gsplit_a, blk, 0, stream>>>(key_, ah_s, al_s);
    gemm_bf16x3<<<ggemm, blk, 0, stream>>>(ah_s, al_s, wh_s, wl_s, bk, k_ws);
    // v
    split_w<<<gsplit_w, blk, 0, stream>>>(Wv, wh_s, wl_s);
    split_a<<<gsplit_a, blk, 0, stream>>>(value, ah_s, al_s);
    gemm_bf16x3<<<ggemm, blk, 0, stream>>>(ah_s, al_s, wh_s, wl_s, bv, v_ws);
    // p = q @ Wp + bp  -> o_ws
    split_w<<<gsplit_w, blk, 0, stream>>>(Wp, wh_s, wl_s);
    split_a<<<gsplit_a, blk, 0, stream>>>(q_ws, ah_s, al_s);
    gemm_bf16x3<<<ggemm, blk, 0, stream>>>(ah_s, al_s, wh_s, wl_s, bp, o_ws);
    // alpha, Gaussian-window params
    alpha_kernel<<<dim3(MTOT / 16), blk, 0, stream>>>(query, Wus, bus, alpha_ws);
    posparam_kernel<<<dim3((BATCH * NHEAD * S_LEN) / 256), blk, 0, stream>>>(
        o_ws, alpha_ws, Wup, bup, Wud, bud, cen_ws, c0_ws);
    // biased scores -> attn region (overwrites split scratch; scratch consumed)
    score_kernel<<<dim3(S_LEN / 128, S_LEN / 128, BATCH * NHEAD), blk, 0, stream>>>(
        q_ws, k_ws, cen_ws, c0_ws, attn);
    // softmax in place
    softmax_kernel<<<dim3(BATCH * NHEAD * S_LEN), blk, 0, stream>>>(attn);
    // out = attn @ vh -> o_ws (overwrites p; p consumed)
    gemm_f32<<<dim3(1, S_LEN / 128, BATCH * NHEAD), blk, 0, stream>>>(
        attn, v_ws, nullptr, o_ws,
        S_LEN, HDIM, S_LEN, S_LEN, HIDN, HIDN, 1);
    // x = out @ Wo + bo
    split_w<<<gsplit_w, blk, 0, stream>>>(Wo, w2h_s, w2l_s);
    split_a<<<gsplit_a, blk, 0, stream>>>(o_ws, oh_s, ol_s);
    gemm_bf16x3<<<ggemm, blk, 0, stream>>>(oh_s, ol_s, w2h_s, w2l_s, bo, x_out);
}

// Round 3
// 573.206 us; speedup vs baseline: 1.7854x; 1.1580x over previous
//
#include <hip/hip_runtime.h>
#include <hip/hip_bf16.h>
#include <math.h>

#define S_LEN 1024
#define HIDN  1024
#define NHEAD 16
#define HDIM  64
#define BATCH 4
#define MTOT  (BATCH * S_LEN)   // 4096

typedef __attribute__((ext_vector_type(8))) short          bf16v8;
typedef __attribute__((ext_vector_type(8))) unsigned short u16v8;
typedef __attribute__((ext_vector_type(4))) unsigned short u16v4;
typedef __attribute__((ext_vector_type(4))) float          f32v4;

// ---------------------------------------------------------------------------
// bf16 hi/lo split helpers (RNE)
// ---------------------------------------------------------------------------
__device__ __forceinline__ unsigned short f2bf_rne(float x) {
    unsigned int u = __float_as_uint(x);
    unsigned int r = (u + 0x7fffu + ((u >> 16) & 1u)) >> 16;
    return (unsigned short)r;
}
__device__ __forceinline__ float bf2f(unsigned short h) {
    return __uint_as_float(((unsigned int)h) << 16);
}
__device__ __forceinline__ void split2(float x, unsigned short& h, unsigned short& l) {
    h = f2bf_rne(x);
    l = f2bf_rne(x - bf2f(h));
}

// ---------------------------------------------------------------------------
// split_a: row-major f32 [M][1024] -> Ah, Al bf16 (same layout).
// ---------------------------------------------------------------------------
__global__ __launch_bounds__(256) void split_a(
    const float* __restrict__ X, unsigned short* __restrict__ H,
    unsigned short* __restrict__ L)
{
    const int i = blockIdx.x * 256 + threadIdx.x;
    const float4 x0 = ((const float4*)X)[2 * i];
    const float4 x1 = ((const float4*)X)[2 * i + 1];
    float xs[8] = {x0.x, x0.y, x0.z, x0.w, x1.x, x1.y, x1.z, x1.w};
    u16v8 h, l;
#pragma unroll
    for (int j = 0; j < 8; ++j) {
        unsigned short hh, ll;
        split2(xs[j], hh, ll);
        h[j] = hh; l[j] = ll;
    }
    ((u16v8*)H)[i] = h;
    ((u16v8*)L)[i] = l;
}

// ---------------------------------------------------------------------------
// split_w: W f32 [K=1024][N=1024] -> transposed Ht, Lt bf16 [N][K] (k-contig).
// ---------------------------------------------------------------------------
__global__ __launch_bounds__(256) void split_w(
    const float* __restrict__ W, unsigned short* __restrict__ H,
    unsigned short* __restrict__ L)
{
    __shared__ float T[64][65];
    const int t  = threadIdx.x;
    const int k0 = blockIdx.y * 64;
    const int n0 = blockIdx.x * 64;

    const int r = t >> 4;
    const int c = (t & 15) * 4;
#pragma unroll
    for (int i = 0; i < 4; ++i) {
        const int rr = r + i * 16;
        const float4 v = *(const float4*)&W[(size_t)(k0 + rr) * 1024 + n0 + c];
        T[rr][c + 0] = v.x; T[rr][c + 1] = v.y;
        T[rr][c + 2] = v.z; T[rr][c + 3] = v.w;
    }
    __syncthreads();

    const int n  = t >> 2;
    const int ko = (t & 3) * 16;
    u16v8 h0, h1, l0, l1;
#pragma unroll
    for (int kk = 0; kk < 8; ++kk) {
        unsigned short hh, ll;
        split2(T[ko + kk][n], hh, ll);
        h0[kk] = hh; l0[kk] = ll;
    }
#pragma unroll
    for (int kk = 0; kk < 8; ++kk) {
        unsigned short hh, ll;
        split2(T[ko + 8 + kk][n], hh, ll);
        h1[kk] = hh; l1[kk] = ll;
    }
    unsigned short* Hp = &H[(size_t)(n0 + n) * 1024 + k0 + ko];
    unsigned short* Lp = &L[(size_t)(n0 + n) * 1024 + k0 + ko];
    *(u16v8*)(Hp)     = h0;
    *(u16v8*)(Hp + 8) = h1;
    *(u16v8*)(Lp)     = l0;
    *(u16v8*)(Lp + 8) = l1;
}

// ---------------------------------------------------------------------------
// bf16x3 MFMA GEMM: C = A(hi/lo bf16 [M][1024]) @ B(hi/lo bf16 [n][k]) + bias.
// BM=BN=128, BK=32, 256 threads (4 waves 2x2), wave 64x64 out.
// Epilogue modes: Cf (f32 row-major) and/or Ch/Cl (bf16 hi/lo);
// vt=1: Ch/Cl written in per-head transposed layout [(b*16+h)*64+d][s].
// ---------------------------------------------------------------------------
__global__ __launch_bounds__(256) void gemm_bf16x3(
    const unsigned short* __restrict__ Ah, const unsigned short* __restrict__ Al,
    const unsigned short* __restrict__ Bh, const unsigned short* __restrict__ Bl,
    const float* __restrict__ bias, float* __restrict__ Cf,
    unsigned short* __restrict__ Ch, unsigned short* __restrict__ Cl, int vt)
{
    __shared__ short Ash[128][40];
    __shared__ short Asl[128][40];
    __shared__ short Bsh[128][40];
    __shared__ short Bsl[128][40];

    const int t    = threadIdx.x;
    const int bm   = blockIdx.y * 128;
    const int bn   = blockIdx.x * 128;
    const int lane = t & 63;
    const int w    = t >> 6;
    const int wr   = w >> 1;
    const int wc   = w & 1;
    const int fr   = lane & 15;
    const int fq   = lane >> 4;
    const int ks   = fq * 8;

    f32v4 zero = {0.f, 0.f, 0.f, 0.f};
    f32v4 acc[4][4];
#pragma unroll
    for (int i = 0; i < 4; ++i)
#pragma unroll
        for (int j = 0; j < 4; ++j) acc[i][j] = zero;

    const int sr = t >> 1;
    const int sc = (t & 1) * 16;
    const unsigned short* pAh = &Ah[(size_t)(bm + sr) * 1024 + sc];
    const unsigned short* pAl = &Al[(size_t)(bm + sr) * 1024 + sc];
    const unsigned short* pBh = &Bh[(size_t)(bn + sr) * 1024 + sc];
    const unsigned short* pBl = &Bl[(size_t)(bn + sr) * 1024 + sc];

    u16v8 rah0, rah1, ral0, ral1, rbh0, rbh1, rbl0, rbl1;
    auto LOAD = [&](int k0) {
        rah0 = *(const u16v8*)(pAh + k0);
        rah1 = *(const u16v8*)(pAh + k0 + 8);
        ral0 = *(const u16v8*)(pAl + k0);
        ral1 = *(const u16v8*)(pAl + k0 + 8);
        rbh0 = *(const u16v8*)(pBh + k0);
        rbh1 = *(const u16v8*)(pBh + k0 + 8);
        rbl0 = *(const u16v8*)(pBl + k0);
        rbl1 = *(const u16v8*)(pBl + k0 + 8);
    };

    LOAD(0);
    for (int k0 = 0; k0 < 1024; k0 += 32) {
        __syncthreads();
        *(u16v8*)&Ash[sr][sc]     = rah0;
        *(u16v8*)&Ash[sr][sc + 8] = rah1;
        *(u16v8*)&Asl[sr][sc]     = ral0;
        *(u16v8*)&Asl[sr][sc + 8] = ral1;
        *(u16v8*)&Bsh[sr][sc]     = rbh0;
        *(u16v8*)&Bsh[sr][sc + 8] = rbh1;
        *(u16v8*)&Bsl[sr][sc]     = rbl0;
        *(u16v8*)&Bsl[sr][sc + 8] = rbl1;
        __syncthreads();

        if (k0 + 32 < 1024) LOAD(k0 + 32);

        bf16v8 fah[4], fal[4], fbh[4], fbl[4];
#pragma unroll
        for (int i = 0; i < 4; ++i) {
            fah[i] = *(const bf16v8*)&Ash[wr * 64 + i * 16 + fr][ks];
            fal[i] = *(const bf16v8*)&Asl[wr * 64 + i * 16 + fr][ks];
            fbh[i] = *(const bf16v8*)&Bsh[wc * 64 + i * 16 + fr][ks];
            fbl[i] = *(const bf16v8*)&Bsl[wc * 64 + i * 16 + fr][ks];
        }
#pragma unroll
        for (int i = 0; i < 4; ++i)
#pragma unroll
            for (int j = 0; j < 4; ++j) {
                acc[i][j] = __builtin_amdgcn_mfma_f32_16x16x32_bf16(
                    fah[i], fbh[j], acc[i][j], 0, 0, 0);
                acc[i][j] = __builtin_amdgcn_mfma_f32_16x16x32_bf16(
                    fah[i], fbl[j], acc[i][j], 0, 0, 0);
                acc[i][j] = __builtin_amdgcn_mfma_f32_16x16x32_bf16(
                    fal[i], fbh[j], acc[i][j], 0, 0, 0);
            }
    }

#pragma unroll
    for (int j = 0; j < 4; ++j) {
        const int col = bn + wc * 64 + j * 16 + fr;
        const float bb = bias[col];
#pragma unroll
        for (int i = 0; i < 4; ++i) {
            const int row0 = bm + wr * 64 + i * 16 + fq * 4;
            const f32v4 cv = acc[i][j];
            if (vt) {
                // per-head transposed bf16: idx = ((b*16+h)*64+d)*1024 + s
                u16v4 h4, l4;
#pragma unroll
                for (int r = 0; r < 4; ++r) {
                    unsigned short hh, ll;
                    split2(cv[r] + bb, hh, ll);
                    h4[r] = hh; l4[r] = ll;
                }
                const size_t base =
                    ((size_t)((row0 >> 10) * 16 + (col >> 6)) * 64 + (col & 63)) * 1024
                    + (row0 & 1023);
                *(u16v4*)&Ch[base] = h4;
                *(u16v4*)&Cl[base] = l4;
            } else {
#pragma unroll
                for (int r = 0; r < 4; ++r) {
                    const float v = cv[r] + bb;
                    const size_t idx = (size_t)(row0 + r) * 1024 + col;
                    if (Cf) Cf[idx] = v;
                    if (Ch) {
                        unsigned short hh, ll;
                        split2(v, hh, ll);
                        Ch[idx] = hh; Cl[idx] = ll;
                    }
                }
            }
        }
    }
}

// ---------------------------------------------------------------------------
// alpha = sigmoid(query @ Wus + bus)   [MTOT,16]
// ---------------------------------------------------------------------------
__global__ __launch_bounds__(256) void alpha_kernel(
    const float* __restrict__ X, const float* __restrict__ Wus,
    const float* __restrict__ bus, float* __restrict__ alpha)
{
    __shared__ float Ws[1024 * 16];
    const int t = threadIdx.x;
#pragma unroll
    for (int i = 0; i < 16; ++i) {
        const int idx = t + i * 256;
        *reinterpret_cast<float4*>(&Ws[idx * 4]) =
            *reinterpret_cast<const float4*>(&Wus[idx * 4]);
    }
    __syncthreads();

    const int r = t >> 4, c = t & 15;
    const size_t row = (size_t)blockIdx.x * 16 + r;
    const float* x = &X[row * 1024];
    float acc = 0.f;
    for (int kk = 0; kk < 1024; kk += 4) {
        const float4 xv = *reinterpret_cast<const float4*>(&x[kk]);
        acc = fmaf(xv.x, Ws[(kk + 0) * 16 + c], acc);
        acc = fmaf(xv.y, Ws[(kk + 1) * 16 + c], acc);
        acc = fmaf(xv.z, Ws[(kk + 2) * 16 + c], acc);
        acc = fmaf(xv.w, Ws[(kk + 3) * 16 + c], acc);
    }
    acc += bus[c];
    alpha[row * 16 + c] = 1.f / (1.f + expf(-acc));
}

// ---------------------------------------------------------------------------
// Gaussian-window parameters per (b,h,s)
// ---------------------------------------------------------------------------
__global__ __launch_bounds__(256) void posparam_kernel(
    const float* __restrict__ p, const float* __restrict__ alpha,
    const float* __restrict__ Wup, const float* __restrict__ bup,
    const float* __restrict__ Wud, const float* __restrict__ bud,
    float* __restrict__ cen, float* __restrict__ c0)
{
    __shared__ float wu[64], wd[64];
    const int t = threadIdx.x;
    if (t < 64) { wu[t] = Wup[t]; wd[t] = Wud[t]; }
    __syncthreads();

    const int tid = blockIdx.x * 256 + t;
    const int b = tid >> 14;
    const int h = (tid >> 10) & 15;
    const int s = tid & 1023;

    const float* pr = &p[((size_t)(b * 1024 + s)) * 1024 + h * 64];
    float ap = 0.f, az = 0.f;
#pragma unroll
    for (int d = 0; d < 64; d += 4) {
        const float4 pv = *reinterpret_cast<const float4*>(&pr[d]);
        const float t0 = tanhf(pv.x), t1 = tanhf(pv.y);
        const float t2 = tanhf(pv.z), t3 = tanhf(pv.w);
        ap += t0 * wu[d] + t1 * wu[d + 1] + t2 * wu[d + 2] + t3 * wu[d + 3];
        az += t0 * wd[d] + t1 * wd[d + 1] + t2 * wd[d + 2] + t3 * wd[d + 3];
    }
    ap += bup[0];
    az += bud[0];
    const float cenv = 1024.f / (1.f + expf(-ap));
    const float win  = 1024.f / (1.f + expf(-az));
    const float al   = alpha[(size_t)(b * 1024 + s) * 16 + h];
    const int oi = (b * 16 + h) * 1024 + s;
    cen[oi] = cenv;
    c0[oi]  = al * 2.f / (win * win);
}

// ---------------------------------------------------------------------------
// score_mfma: raw scores[z,i,j] = (q_i.k_j)*0.125 - c0[z,i]*(j-cen[z,i])^2
// bf16x3 MFMA NT, tile 128x128 per block, d=64 single shot.
// LDS tiles [128][64] shorts (128B rows) with XOR slot swizzle (G4).
// ---------------------------------------------------------------------------
__global__ __launch_bounds__(256) void score_mfma(
    const unsigned short* __restrict__ qh, const unsigned short* __restrict__ ql,
    const unsigned short* __restrict__ kh, const unsigned short* __restrict__ kl,
    const float* __restrict__ cen, const float* __restrict__ c0,
    float* __restrict__ attn)
{
    __shared__ unsigned short QH[128][64], QL[128][64];
    __shared__ unsigned short KH[128][64], KL[128][64];
    __shared__ float CEN[128], C0S[128];

    const int t  = threadIdx.x;
    const int z  = blockIdx.z;
    const int i0 = blockIdx.y * 128;
    const int j0 = blockIdx.x * 128;
    const int bq = z >> 4, hh = z & 15;

    if (t < 128) {
        CEN[t] = cen[(size_t)z * 1024 + i0 + t];
        C0S[t] = c0[(size_t)z * 1024 + i0 + t];
    }

    // stage q/k tiles: idx -> row (0..127), seg (0..7); swizzled 16B slot
#pragma unroll
    for (int p = 0; p < 4; ++p) {
        const int idx = t + p * 256;
        const int row = idx >> 3;
        const int seg = idx & 7;
        const int sl  = (seg ^ (row & 7)) * 8;
        const size_t qa = (size_t)(bq * 1024 + i0 + row) * 1024 + hh * 64 + seg * 8;
        const size_t ka = (size_t)(bq * 1024 + j0 + row) * 1024 + hh * 64 + seg * 8;
        *(u16v8*)&QH[row][sl] = *(const u16v8*)&qh[qa];
        *(u16v8*)&QL[row][sl] = *(const u16v8*)&ql[qa];
        *(u16v8*)&KH[row][sl] = *(const u16v8*)&kh[ka];
        *(u16v8*)&KL[row][sl] = *(const u16v8*)&kl[ka];
    }
    __syncthreads();

    const int lane = t & 63;
    const int w  = t >> 6;
    const int wr = w >> 1, wc = w & 1;
    const int fr = lane & 15, fq = lane >> 4;

    f32v4 zero = {0.f, 0.f, 0.f, 0.f};
    f32v4 acc[4][4];
#pragma unroll
    for (int i = 0; i < 4; ++i)
#pragma unroll
        for (int j = 0; j < 4; ++j) acc[i][j] = zero;

#pragma unroll
    for (int kk = 0; kk < 2; ++kk) {
        bf16v8 fah[4], fal[4], fbh[4], fbl[4];
#pragma unroll
        for (int i = 0; i < 4; ++i) {
            const int ra = wr * 64 + i * 16 + fr;
            const int sa = (((kk * 4 + fq) ^ (ra & 7))) * 8;
            fah[i] = *(const bf16v8*)&QH[ra][sa];
            fal[i] = *(const bf16v8*)&QL[ra][sa];
            const int rb = wc * 64 + i * 16 + fr;
            const int sb = (((kk * 4 + fq) ^ (rb & 7))) * 8;
            fbh[i] = *(const bf16v8*)&KH[rb][sb];
            fbl[i] = *(const bf16v8*)&KL[rb][sb];
        }
#pragma unroll
        for (int i = 0; i < 4; ++i)
#pragma unroll
            for (int j = 0; j < 4; ++j) {
                acc[i][j] = __builtin_amdgcn_mfma_f32_16x16x32_bf16(
                    fah[i], fbh[j], acc[i][j], 0, 0, 0);
                acc[i][j] = __builtin_amdgcn_mfma_f32_16x16x32_bf16(
                    fah[i], fbl[j], acc[i][j], 0, 0, 0);
                acc[i][j] = __builtin_amdgcn_mfma_f32_16x16x32_bf16(
                    fal[i], fbh[j], acc[i][j], 0, 0, 0);
            }
    }

#pragma unroll
    for (int i = 0; i < 4; ++i) {
#pragma unroll
        for (int r = 0; r < 4; ++r) {
            const int rl   = wr * 64 + i * 16 + fq * 4 + r;
            const float cv = CEN[rl];
            const float c2 = C0S[rl];
#pragma unroll
            for (int j = 0; j < 4; ++j) {
                const int cl = wc * 64 + j * 16 + fr;
                const float jf = (float)(j0 + cl);
                const float dd = jf - cv;
                attn[(size_t)z * 1024 * 1024 + (size_t)(i0 + rl) * 1024 + j0 + cl] =
                    acc[i][j][r] * 0.125f - c2 * dd * dd;
            }
        }
    }
}

// ---------------------------------------------------------------------------
// rowstat: per row of raw scores, m = max, rinv = 1/sum(exp(s-m))
// ---------------------------------------------------------------------------
__global__ __launch_bounds__(256) void rowstat_kernel(
    const float* __restrict__ attn, float* __restrict__ rowm,
    float* __restrict__ rowrl)
{
    __shared__ float red[8];
    const size_t row = blockIdx.x;
    const float* p = attn + row * 1024;
    const int t = threadIdx.x;

    const float4 v = *reinterpret_cast<const float4*>(&p[t * 4]);
    float m = fmaxf(fmaxf(v.x, v.y), fmaxf(v.z, v.w));
#pragma unroll
    for (int off = 1; off < 64; off <<= 1) m = fmaxf(m, __shfl_xor(m, off));
    if ((t & 63) == 0) red[t >> 6] = m;
    __syncthreads();
    m = fmaxf(fmaxf(red[0], red[1]), fmaxf(red[2], red[3]));

    float s = __expf(v.x - m) + __expf(v.y - m) + __expf(v.z - m) + __expf(v.w - m);
#pragma unroll
    for (int off = 1; off < 64; off <<= 1) s += __shfl_xor(s, off);
    if ((t & 63) == 0) red[4 + (t >> 6)] = s;
    __syncthreads();
    s = red[4] + red[5] + red[6] + red[7];

    if (t == 0) {
        rowm[row]  = m;
        rowrl[row] = 1.f / s;
    }
}

// ---------------------------------------------------------------------------
// pv_fused: reads raw scores, writes normalized attn f32 (output), and
// computes out = attn @ v via bf16x3 MFMA with V pre-transposed [z][d][s].
// Block: (i-tile 128 rows, z). Loops 16 j-tiles of 64.
// ---------------------------------------------------------------------------
__global__ __launch_bounds__(256) void pv_fused(
    float* __restrict__ attn,
    const unsigned short* __restrict__ vTh, const unsigned short* __restrict__ vTl,
    const float* __restrict__ rowm, const float* __restrict__ rowrl,
    unsigned short* __restrict__ oh, unsigned short* __restrict__ ol)
{
    __shared__ unsigned short PH[128][64], PL[128][64];
    __shared__ unsigned short VH[64][64],  VL[64][64];
    __shared__ float SM[128], SR[128];

    const int t  = threadIdx.x;
    const int i0 = blockIdx.x * 128;
    const int z  = blockIdx.y;

    if (t < 128) {
        SM[t] = rowm[(size_t)z * 1024 + i0 + t];
        SR[t] = rowrl[(size_t)z * 1024 + i0 + t];
    }
    __syncthreads();

    const int lane = t & 63;
    const int w  = t >> 6;
    const int wr = w >> 1, wc = w & 1;
    const int fr = lane & 15, fq = lane >> 4;

    f32v4 zero = {0.f, 0.f, 0.f, 0.f};
    f32v4 acc[4][2];
#pragma unroll
    for (int i = 0; i < 4; ++i)
#pragma unroll
        for (int j = 0; j < 2; ++j) acc[i][j] = zero;

    float* Sbase = attn + (size_t)z * 1024 * 1024 + (size_t)i0 * 1024;
    const unsigned short* vhb = vTh + (size_t)z * 64 * 1024;
    const unsigned short* vlb = vTl + (size_t)z * 64 * 1024;

    for (int jt = 0; jt < 16; ++jt) {
        const int j0 = jt * 64;

        // ---- stage P: 128 rows x 64 cols, 8-float chunks
#pragma unroll
        for (int p = 0; p < 4; ++p) {
            const int c   = t + p * 256;       // 0..1023
            const int row = c >> 3;
            const int seg = c & 7;
            float* sp = Sbase + (size_t)row * 1024 + j0 + seg * 8;
            float4 a = *(float4*)sp;
            float4 b = *(float4*)(sp + 4);
            const float m = SM[row], ri = SR[row];
            a.x = __expf(a.x - m) * ri; a.y = __expf(a.y - m) * ri;
            a.z = __expf(a.z - m) * ri; a.w = __expf(a.w - m) * ri;
            b.x = __expf(b.x - m) * ri; b.y = __expf(b.y - m) * ri;
            b.z = __expf(b.z - m) * ri; b.w = __expf(b.w - m) * ri;
            *(float4*)sp = a;
            *(float4*)(sp + 4) = b;
            const float vals[8] = {a.x, a.y, a.z, a.w, b.x, b.y, b.z, b.w};
            u16v8 h8, l8;
#pragma unroll
            for (int e = 0; e < 8; ++e) {
                unsigned short hh, ll;
                split2(vals[e], hh, ll);
                h8[e] = hh; l8[e] = ll;
            }
            const int sl = (seg ^ (row & 7)) * 8;
            *(u16v8*)&PH[row][sl] = h8;
            *(u16v8*)&PL[row][sl] = l8;
        }
        // ---- stage Vt: 64 rows (d) x 64 cols (j)
#pragma unroll
        for (int p = 0; p < 2; ++p) {
            const int c   = t + p * 256;       // 0..511
            const int d   = c >> 3;
            const int seg = c & 7;
            const size_t ga = (size_t)d * 1024 + j0 + seg * 8;
            const int sl = (seg ^ (d & 7)) * 8;
            *(u16v8*)&VH[d][sl] = *(const u16v8*)&vhb[ga];
            *(u16v8*)&VL[d][sl] = *(const u16v8*)&vlb[ga];
        }
        __syncthreads();

        // ---- MFMA: wave out 64 rows x 32 d; k = 64 (2 steps)
#pragma unroll
        for (int kk = 0; kk < 2; ++kk) {
            bf16v8 pah[4], pal[4], fbh[2], fbl[2];
#pragma unroll
            for (int i = 0; i < 4; ++i) {
                const int ra = wr * 64 + i * 16 + fr;
                const int sa = ((kk * 4 + fq) ^ (ra & 7)) * 8;
                pah[i] = *(const bf16v8*)&PH[ra][sa];
                pal[i] = *(const bf16v8*)&PL[ra][sa];
            }
#pragma unroll
            for (int j = 0; j < 2; ++j) {
                const int rb = wc * 32 + j * 16 + fr;
                const int sb = ((kk * 4 + fq) ^ (rb & 7)) * 8;
                fbh[j] = *(const bf16v8*)&VH[rb][sb];
                fbl[j] = *(const bf16v8*)&VL[rb][sb];
            }
#pragma unroll
            for (int i = 0; i < 4; ++i)
#pragma unroll
                for (int j = 0; j < 2; ++j) {
                    acc[i][j] = __builtin_amdgcn_mfma_f32_16x16x32_bf16(
                        pah[i], fbh[j], acc[i][j], 0, 0, 0);
                    acc[i][j] = __builtin_amdgcn_mfma_f32_16x16x32_bf16(
                        pah[i], fbl[j], acc[i][j], 0, 0, 0);
                    acc[i][j] = __builtin_amdgcn_mfma_f32_16x16x32_bf16(
                        pal[i], fbh[j], acc[i][j], 0, 0, 0);
                }
        }
        __syncthreads();
    }

    // ---- epilogue: o row-major [4096][1024], col = h*64 + d, bf16 hi/lo
    const int b = z >> 4, hh = z & 15;
#pragma unroll
    for (int j = 0; j < 2; ++j) {
        const int dcol = wc * 32 + j * 16 + fr;
#pragma unroll
        for (int i = 0; i < 4; ++i) {
            const int row0 = i0 + wr * 64 + i * 16 + fq * 4;
            const f32v4 cv = acc[i][j];
#pragma unroll
            for (int r = 0; r < 4; ++r) {
                unsigned short hv, lv;
                split2(cv[r], hv, lv);
                const size_t idx = (size_t)(b * 1024 + row0 + r) * 1024 + hh * 64 + dcol;
                oh[idx] = hv;
                ol[idx] = lv;
            }
        }
    }
}

// ---------------------------------------------------------------------------
extern "C" void kernel_launch(void* const* d_in, const int* in_sizes, int n_in,
                              void* d_out, int out_size, void* d_ws, size_t ws_size,
                              hipStream_t stream)
{
    const float* query = (const float*)d_in[0];
    const float* key_  = (const float*)d_in[1];
    const float* value = (const float*)d_in[2];
    const float* Wq  = (const float*)d_in[3];
    const float* bq  = (const float*)d_in[4];
    const float* Wk  = (const float*)d_in[5];
    const float* bk  = (const float*)d_in[6];
    const float* Wv  = (const float*)d_in[7];
    const float* bv  = (const float*)d_in[8];
    const float* Wp  = (const float*)d_in[9];
    const float* bp  = (const float*)d_in[10];
    const float* Wup = (const float*)d_in[11];
    const float* bup = (const float*)d_in[12];
    const float* Wud = (const float*)d_in[13];
    const float* bud = (const float*)d_in[14];
    const float* Wus = (const float*)d_in[15];
    const float* bus = (const float*)d_in[16];
    const float* Wo  = (const float*)d_in[17];
    const float* bo  = (const float*)d_in[18];

    float* x_out = (float*)d_out;                         // [4096,1024]
    float* attn  = x_out + (size_t)MTOT * HIDN;           // [64,1024,1024]

    // ---- workspace layout (bytes)
    char* wsb = (char*)d_ws;
    unsigned short* qh  = (unsigned short*)(wsb);                  // 8 MB
    unsigned short* ql  = (unsigned short*)(wsb + (8u  << 20));
    unsigned short* kh  = (unsigned short*)(wsb + (16u << 20));
    unsigned short* kl  = (unsigned short*)(wsb + (24u << 20));
    unsigned short* vTh = (unsigned short*)(wsb + (32u << 20));
    unsigned short* vTl = (unsigned short*)(wsb + (40u << 20));
    float* p_ws  = (float*)(wsb + (48u << 20));                    // 16 MB
    unsigned short* oh = (unsigned short*)(wsb + (48u << 20));     // overlays p
    unsigned short* ol = (unsigned short*)(wsb + (56u << 20));
    float* alpha_ws = (float*)(wsb + (64u << 20));                 // 256 KB
    float* cen_ws   = (float*)(wsb + (64u << 20) + (256u << 10));
    float* c0_ws    = (float*)(wsb + (64u << 20) + (512u << 10));
    float* rowm_ws  = (float*)(wsb + (64u << 20) + (768u << 10));
    float* rowrl_ws = (float*)(wsb + (65u << 20));
    // weight-split scratch for stage 1 lives in the (not-yet-written) attn region
    unsigned short* ah = (unsigned short*)attn;                    // 8 MB
    unsigned short* al = ah + (size_t)MTOT * HIDN;                 // 8 MB
    unsigned short* wh = al + (size_t)MTOT * HIDN;                 // 2 MB
    unsigned short* wl = wh + (size_t)HIDN * HIDN;                 // 2 MB
    // Wo split reuses qh/ql space after score_mfma
    unsigned short* w2h = qh;
    unsigned short* w2l = ql;

    const dim3 blk(256);
    const dim3 gsplit_a(MTOT * HIDN / 8 / 256);
    const dim3 gsplit_w(16, 16);
    const dim3 ggemm(HIDN / 128, MTOT / 128);

    // q = query @ Wq + bq -> qh/ql (bf16 only)
    split_w<<<gsplit_w, blk, 0, stream>>>(Wq, wh, wl);
    split_a<<<gsplit_a, blk, 0, stream>>>(query, ah, al);
    gemm_bf16x3<<<ggemm, blk, 0, stream>>>(ah, al, wh, wl, bq, nullptr, qh, ql, 0);
    // k -> kh/kl
    split_w<<<gsplit_w, blk, 0, stream>>>(Wk, wh, wl);
    split_a<<<gsplit_a, blk, 0, stream>>>(key_, ah, al);
    gemm_bf16x3<<<ggemm, blk, 0, stream>>>(ah, al, wh, wl, bk, nullptr, kh, kl, 0);
    // v -> vTh/vTl (per-head transposed)
    split_w<<<gsplit_w, blk, 0, stream>>>(Wv, wh, wl);
    split_a<<<gsplit_a, blk, 0, stream>>>(value, ah, al);
    gemm_bf16x3<<<ggemm, blk, 0, stream>>>(ah, al, wh, wl, bv, nullptr, vTh, vTl, 1);
    // p = q @ Wp + bp -> p_ws (f32); A is already-split qh/ql
    split_w<<<gsplit_w, blk, 0, stream>>>(Wp, wh, wl);
    gemm_bf16x3<<<ggemm, blk, 0, stream>>>(qh, ql, wh, wl, bp, p_ws, nullptr, nullptr, 0);
    // alpha + window params
    alpha_kernel<<<dim3(MTOT / 16), blk, 0, stream>>>(query, Wus, bus, alpha_ws);
    posparam_kernel<<<dim3((BATCH * NHEAD * S_LEN) / 256), blk, 0, stream>>>(
        p_ws, alpha_ws, Wup, bup, Wud, bud, cen_ws, c0_ws);
    // raw scores -> attn region (consumes ah/al/wh/wl scratch)
    score_mfma<<<dim3(S_LEN / 128, S_LEN / 128, BATCH * NHEAD), blk, 0, stream>>>(
        qh, ql, kh, kl, cen_ws, c0_ws, attn);
    // row stats
    rowstat_kernel<<<dim3(BATCH * NHEAD * S_LEN), blk, 0, stream>>>(
        attn, rowm_ws, rowrl_ws);
    // softmax-normalize attn in place + PV -> oh/ol
    pv_fused<<<dim3(S_LEN / 128, BATCH * NHEAD), blk, 0, stream>>>(
        attn, vTh, vTl, rowm_ws, rowrl_ws, oh, ol);
    // x = o @ Wo + bo
    split_w<<<gsplit_w, blk, 0, stream>>>(Wo, w2h, w2l);
    gemm_bf16x3<<<ggemm, blk, 0, stream>>>(oh, ol, w2h, w2l, bo, x_out,
                                           nullptr, nullptr, 0);
}

// Round 4
// 440.579 us; speedup vs baseline: 2.3228x; 1.3010x over previous
//
#include <hip/hip_runtime.h>
#include <hip/hip_bf16.h>
#include <math.h>

#define S_LEN 1024
#define HIDN  1024
#define NHEAD 16
#define HDIM  64
#define BATCH 4
#define MTOT  (BATCH * S_LEN)   // 4096

typedef __attribute__((ext_vector_type(8))) short          bf16v8;
typedef __attribute__((ext_vector_type(8))) unsigned short u16v8;
typedef __attribute__((ext_vector_type(4))) unsigned short u16v4;
typedef __attribute__((ext_vector_type(4))) float          f32v4;

// ---------------------------------------------------------------------------
// bf16 hi/lo split helpers (RNE)
// ---------------------------------------------------------------------------
__device__ __forceinline__ unsigned short f2bf_rne(float x) {
    unsigned int u = __float_as_uint(x);
    unsigned int r = (u + 0x7fffu + ((u >> 16) & 1u)) >> 16;
    return (unsigned short)r;
}
__device__ __forceinline__ float bf2f(unsigned short h) {
    return __uint_as_float(((unsigned int)h) << 16);
}
__device__ __forceinline__ void split2(float x, unsigned short& h, unsigned short& l) {
    h = f2bf_rne(x);
    l = f2bf_rne(x - bf2f(h));
}

// ---------------------------------------------------------------------------
// split_a: row-major f32 [M][1024] -> Ah, Al bf16 (same layout).
// ---------------------------------------------------------------------------
__global__ __launch_bounds__(256) void split_a(
    const float* __restrict__ X, unsigned short* __restrict__ H,
    unsigned short* __restrict__ L)
{
    const int i = blockIdx.x * 256 + threadIdx.x;
    const float4 x0 = ((const float4*)X)[2 * i];
    const float4 x1 = ((const float4*)X)[2 * i + 1];
    float xs[8] = {x0.x, x0.y, x0.z, x0.w, x1.x, x1.y, x1.z, x1.w};
    u16v8 h, l;
#pragma unroll
    for (int j = 0; j < 8; ++j) {
        unsigned short hh, ll;
        split2(xs[j], hh, ll);
        h[j] = hh; l[j] = ll;
    }
    ((u16v8*)H)[i] = h;
    ((u16v8*)L)[i] = l;
}

// ---------------------------------------------------------------------------
// split_w: W f32 [K=1024][N=1024] -> transposed Ht, Lt bf16 [N][K] (k-contig).
// ---------------------------------------------------------------------------
__global__ __launch_bounds__(256) void split_w(
    const float* __restrict__ W, unsigned short* __restrict__ H,
    unsigned short* __restrict__ L)
{
    __shared__ float T[64][65];
    const int t  = threadIdx.x;
    const int k0 = blockIdx.y * 64;
    const int n0 = blockIdx.x * 64;

    const int r = t >> 4;
    const int c = (t & 15) * 4;
#pragma unroll
    for (int i = 0; i < 4; ++i) {
        const int rr = r + i * 16;
        const float4 v = *(const float4*)&W[(size_t)(k0 + rr) * 1024 + n0 + c];
        T[rr][c + 0] = v.x; T[rr][c + 1] = v.y;
        T[rr][c + 2] = v.z; T[rr][c + 3] = v.w;
    }
    __syncthreads();

    const int n  = t >> 2;
    const int ko = (t & 3) * 16;
    u16v8 h0, h1, l0, l1;
#pragma unroll
    for (int kk = 0; kk < 8; ++kk) {
        unsigned short hh, ll;
        split2(T[ko + kk][n], hh, ll);
        h0[kk] = hh; l0[kk] = ll;
    }
#pragma unroll
    for (int kk = 0; kk < 8; ++kk) {
        unsigned short hh, ll;
        split2(T[ko + 8 + kk][n], hh, ll);
        h1[kk] = hh; l1[kk] = ll;
    }
    unsigned short* Hp = &H[(size_t)(n0 + n) * 1024 + k0 + ko];
    unsigned short* Lp = &L[(size_t)(n0 + n) * 1024 + k0 + ko];
    *(u16v8*)(Hp)     = h0;
    *(u16v8*)(Hp + 8) = h1;
    *(u16v8*)(Lp)     = l0;
    *(u16v8*)(Lp + 8) = l1;
}

// ---------------------------------------------------------------------------
// bf16x3 MFMA GEMM (unchanged, proven): C = A @ B + bias, epilogue modes.
// ---------------------------------------------------------------------------
__global__ __launch_bounds__(256) void gemm_bf16x3(
    const unsigned short* __restrict__ Ah, const unsigned short* __restrict__ Al,
    const unsigned short* __restrict__ Bh, const unsigned short* __restrict__ Bl,
    const float* __restrict__ bias, float* __restrict__ Cf,
    unsigned short* __restrict__ Ch, unsigned short* __restrict__ Cl, int vt)
{
    __shared__ short Ash[128][40];
    __shared__ short Asl[128][40];
    __shared__ short Bsh[128][40];
    __shared__ short Bsl[128][40];

    const int t    = threadIdx.x;
    const int bm   = blockIdx.y * 128;
    const int bn   = blockIdx.x * 128;
    const int lane = t & 63;
    const int w    = t >> 6;
    const int wr   = w >> 1;
    const int wc   = w & 1;
    const int fr   = lane & 15;
    const int fq   = lane >> 4;
    const int ks   = fq * 8;

    f32v4 zero = {0.f, 0.f, 0.f, 0.f};
    f32v4 acc[4][4];
#pragma unroll
    for (int i = 0; i < 4; ++i)
#pragma unroll
        for (int j = 0; j < 4; ++j) acc[i][j] = zero;

    const int sr = t >> 1;
    const int sc = (t & 1) * 16;
    const unsigned short* pAh = &Ah[(size_t)(bm + sr) * 1024 + sc];
    const unsigned short* pAl = &Al[(size_t)(bm + sr) * 1024 + sc];
    const unsigned short* pBh = &Bh[(size_t)(bn + sr) * 1024 + sc];
    const unsigned short* pBl = &Bl[(size_t)(bn + sr) * 1024 + sc];

    u16v8 rah0, rah1, ral0, ral1, rbh0, rbh1, rbl0, rbl1;
    auto LOAD = [&](int k0) {
        rah0 = *(const u16v8*)(pAh + k0);
        rah1 = *(const u16v8*)(pAh + k0 + 8);
        ral0 = *(const u16v8*)(pAl + k0);
        ral1 = *(const u16v8*)(pAl + k0 + 8);
        rbh0 = *(const u16v8*)(pBh + k0);
        rbh1 = *(const u16v8*)(pBh + k0 + 8);
        rbl0 = *(const u16v8*)(pBl + k0);
        rbl1 = *(const u16v8*)(pBl + k0 + 8);
    };

    LOAD(0);
    for (int k0 = 0; k0 < 1024; k0 += 32) {
        __syncthreads();
        *(u16v8*)&Ash[sr][sc]     = rah0;
        *(u16v8*)&Ash[sr][sc + 8] = rah1;
        *(u16v8*)&Asl[sr][sc]     = ral0;
        *(u16v8*)&Asl[sr][sc + 8] = ral1;
        *(u16v8*)&Bsh[sr][sc]     = rbh0;
        *(u16v8*)&Bsh[sr][sc + 8] = rbh1;
        *(u16v8*)&Bsl[sr][sc]     = rbl0;
        *(u16v8*)&Bsl[sr][sc + 8] = rbl1;
        __syncthreads();

        if (k0 + 32 < 1024) LOAD(k0 + 32);

        bf16v8 fah[4], fal[4], fbh[4], fbl[4];
#pragma unroll
        for (int i = 0; i < 4; ++i) {
            fah[i] = *(const bf16v8*)&Ash[wr * 64 + i * 16 + fr][ks];
            fal[i] = *(const bf16v8*)&Asl[wr * 64 + i * 16 + fr][ks];
            fbh[i] = *(const bf16v8*)&Bsh[wc * 64 + i * 16 + fr][ks];
            fbl[i] = *(const bf16v8*)&Bsl[wc * 64 + i * 16 + fr][ks];
        }
#pragma unroll
        for (int i = 0; i < 4; ++i)
#pragma unroll
            for (int j = 0; j < 4; ++j) {
                acc[i][j] = __builtin_amdgcn_mfma_f32_16x16x32_bf16(
                    fah[i], fbh[j], acc[i][j], 0, 0, 0);
                acc[i][j] = __builtin_amdgcn_mfma_f32_16x16x32_bf16(
                    fah[i], fbl[j], acc[i][j], 0, 0, 0);
                acc[i][j] = __builtin_amdgcn_mfma_f32_16x16x32_bf16(
                    fal[i], fbh[j], acc[i][j], 0, 0, 0);
            }
    }

#pragma unroll
    for (int j = 0; j < 4; ++j) {
        const int col = bn + wc * 64 + j * 16 + fr;
        const float bb = bias[col];
#pragma unroll
        for (int i = 0; i < 4; ++i) {
            const int row0 = bm + wr * 64 + i * 16 + fq * 4;
            const f32v4 cv = acc[i][j];
            if (vt) {
                u16v4 h4, l4;
#pragma unroll
                for (int r = 0; r < 4; ++r) {
                    unsigned short hh, ll;
                    split2(cv[r] + bb, hh, ll);
                    h4[r] = hh; l4[r] = ll;
                }
                const size_t base =
                    ((size_t)((row0 >> 10) * 16 + (col >> 6)) * 64 + (col & 63)) * 1024
                    + (row0 & 1023);
                *(u16v4*)&Ch[base] = h4;
                *(u16v4*)&Cl[base] = l4;
            } else {
#pragma unroll
                for (int r = 0; r < 4; ++r) {
                    const float v = cv[r] + bb;
                    const size_t idx = (size_t)(row0 + r) * 1024 + col;
                    if (Cf) Cf[idx] = v;
                    if (Ch) {
                        unsigned short hh, ll;
                        split2(v, hh, ll);
                        Ch[idx] = hh; Cl[idx] = ll;
                    }
                }
            }
        }
    }
}

// ---------------------------------------------------------------------------
// alpha = sigmoid(query @ Wus + bus)   [MTOT,16]
// ---------------------------------------------------------------------------
__global__ __launch_bounds__(256) void alpha_kernel(
    const float* __restrict__ X, const float* __restrict__ Wus,
    const float* __restrict__ bus, float* __restrict__ alpha)
{
    __shared__ float Ws[1024 * 16];
    const int t = threadIdx.x;
#pragma unroll
    for (int i = 0; i < 16; ++i) {
        const int idx = t + i * 256;
        *reinterpret_cast<float4*>(&Ws[idx * 4]) =
            *reinterpret_cast<const float4*>(&Wus[idx * 4]);
    }
    __syncthreads();

    const int r = t >> 4, c = t & 15;
    const size_t row = (size_t)blockIdx.x * 16 + r;
    const float* x = &X[row * 1024];
    float acc = 0.f;
    for (int kk = 0; kk < 1024; kk += 4) {
        const float4 xv = *reinterpret_cast<const float4*>(&x[kk]);
        acc = fmaf(xv.x, Ws[(kk + 0) * 16 + c], acc);
        acc = fmaf(xv.y, Ws[(kk + 1) * 16 + c], acc);
        acc = fmaf(xv.z, Ws[(kk + 2) * 16 + c], acc);
        acc = fmaf(xv.w, Ws[(kk + 3) * 16 + c], acc);
    }
    acc += bus[c];
    alpha[row * 16 + c] = 1.f / (1.f + expf(-acc));
}

// ---------------------------------------------------------------------------
// Gaussian-window parameters per (b,h,s)
// ---------------------------------------------------------------------------
__global__ __launch_bounds__(256) void posparam_kernel(
    const float* __restrict__ p, const float* __restrict__ alpha,
    const float* __restrict__ Wup, const float* __restrict__ bup,
    const float* __restrict__ Wud, const float* __restrict__ bud,
    float* __restrict__ cen, float* __restrict__ c0)
{
    __shared__ float wu[64], wd[64];
    const int t = threadIdx.x;
    if (t < 64) { wu[t] = Wup[t]; wd[t] = Wud[t]; }
    __syncthreads();

    const int tid = blockIdx.x * 256 + t;
    const int b = tid >> 14;
    const int h = (tid >> 10) & 15;
    const int s = tid & 1023;

    const float* pr = &p[((size_t)(b * 1024 + s)) * 1024 + h * 64];
    float ap = 0.f, az = 0.f;
#pragma unroll
    for (int d = 0; d < 64; d += 4) {
        const float4 pv = *reinterpret_cast<const float4*>(&pr[d]);
        const float t0 = tanhf(pv.x), t1 = tanhf(pv.y);
        const float t2 = tanhf(pv.z), t3 = tanhf(pv.w);
        ap += t0 * wu[d] + t1 * wu[d + 1] + t2 * wu[d + 2] + t3 * wu[d + 3];
        az += t0 * wd[d] + t1 * wd[d + 1] + t2 * wd[d + 2] + t3 * wd[d + 3];
    }
    ap += bup[0];
    az += bud[0];
    const float cenv = 1024.f / (1.f + expf(-ap));
    const float win  = 1024.f / (1.f + expf(-az));
    const float al   = alpha[(size_t)(b * 1024 + s) * 16 + h];
    const int oi = (b * 16 + h) * 1024 + s;
    cen[oi] = cenv;
    c0[oi]  = al * 2.f / (win * win);
}

// ---------------------------------------------------------------------------
// attn_fused: per (z, 128-row i-tile), two-pass flash attention.
//  Pass A: recompute S tiles (bf16x3 MFMA), accumulate l = sum exp(s - 8)
//          per thread (no cross-lane in loop); reduce -> RINV[128].
//  Pass B: recompute S, write attn = exp(s-8)*rinv (f32, the output),
//          scatter P bf16 hi/lo into swizzled LDS, PV MFMA -> oh/ol.
// Fixed shift M0=8 is safe: scores bounded above (~3), bounded below at
// j≈cen (≥ ~-10), so no overflow and no all-underflow row.
// ---------------------------------------------------------------------------
#define M0_SHIFT 8.0f
__global__ __launch_bounds__(256, 2) void attn_fused(
    const unsigned short* __restrict__ qh, const unsigned short* __restrict__ ql,
    const unsigned short* __restrict__ kh, const unsigned short* __restrict__ kl,
    const unsigned short* __restrict__ vTh, const unsigned short* __restrict__ vTl,
    const float* __restrict__ cen, const float* __restrict__ c0,
    float* __restrict__ attn,
    unsigned short* __restrict__ oh, unsigned short* __restrict__ ol)
{
    __shared__ unsigned short KH[64][64], KL[64][64];
    __shared__ unsigned short VH[64][64], VL[64][64];
    __shared__ unsigned short PH[128][64], PL[128][64];
    __shared__ float CEN[128], C0S[128];
    __shared__ float LSUM[2][128];
    __shared__ float RINV[128];

    // XCD-bijective mapping: all 8 i-tiles of one z land on one XCD
    const int bid   = blockIdx.x;
    const int z     = ((bid >> 6) << 3) | (bid & 7);
    const int itile = (bid >> 3) & 7;
    const int i0    = itile * 128;
    const int bq    = z >> 4;
    const int hd    = z & 15;

    const int t    = threadIdx.x;
    const int lane = t & 63;
    const int w    = t >> 6;
    const int wr   = w >> 1, wc = w & 1;
    const int fr   = lane & 15, fq = lane >> 4;

    if (t < 128) {
        CEN[t] = cen[(size_t)z * 1024 + i0 + t];
        C0S[t] = c0[(size_t)z * 1024 + i0 + t];
    }

    // Q fragments in registers (A-frag: row = fr, k = kk*32 + fq*8)
    bf16v8 qfh_[4][2], qfl_[4][2];
#pragma unroll
    for (int i = 0; i < 4; ++i)
#pragma unroll
        for (int kk = 0; kk < 2; ++kk) {
            const size_t qa = (size_t)(bq * 1024 + i0 + wr * 64 + i * 16 + fr) * 1024
                              + hd * 64 + kk * 32 + fq * 8;
            qfh_[i][kk] = *(const bf16v8*)&qh[qa];
            qfl_[i][kk] = *(const bf16v8*)&ql[qa];
        }

    float lsum[4][4];
#pragma unroll
    for (int i = 0; i < 4; ++i)
#pragma unroll
        for (int r = 0; r < 4; ++r) lsum[i][r] = 0.f;

    const f32v4 zero = {0.f, 0.f, 0.f, 0.f};

    // ---------------- PASS A: row sums ----------------
    for (int jt = 0; jt < 16; ++jt) {
        const int j0 = jt * 64;
        __syncthreads();
#pragma unroll
        for (int pp = 0; pp < 2; ++pp) {
            const int c   = t + pp * 256;
            const int row = c >> 3;
            const int seg = c & 7;
            const size_t ga = (size_t)(bq * 1024 + j0 + row) * 1024 + hd * 64 + seg * 8;
            const int sl = (seg ^ (row & 7)) * 8;
            *(u16v8*)&KH[row][sl] = *(const u16v8*)&kh[ga];
            *(u16v8*)&KL[row][sl] = *(const u16v8*)&kl[ga];
        }
        __syncthreads();

        f32v4 acc[4][2];
#pragma unroll
        for (int i = 0; i < 4; ++i)
#pragma unroll
            for (int j2 = 0; j2 < 2; ++j2) acc[i][j2] = zero;

#pragma unroll
        for (int kk = 0; kk < 2; ++kk) {
            bf16v8 fbh[2], fbl[2];
#pragma unroll
            for (int j2 = 0; j2 < 2; ++j2) {
                const int rb = wc * 32 + j2 * 16 + fr;
                const int sb = ((kk * 4 + fq) ^ (rb & 7)) * 8;
                fbh[j2] = *(const bf16v8*)&KH[rb][sb];
                fbl[j2] = *(const bf16v8*)&KL[rb][sb];
            }
#pragma unroll
            for (int i = 0; i < 4; ++i)
#pragma unroll
                for (int j2 = 0; j2 < 2; ++j2) {
                    acc[i][j2] = __builtin_amdgcn_mfma_f32_16x16x32_bf16(
                        qfh_[i][kk], fbh[j2], acc[i][j2], 0, 0, 0);
                    acc[i][j2] = __builtin_amdgcn_mfma_f32_16x16x32_bf16(
                        qfh_[i][kk], fbl[j2], acc[i][j2], 0, 0, 0);
                    acc[i][j2] = __builtin_amdgcn_mfma_f32_16x16x32_bf16(
                        qfl_[i][kk], fbh[j2], acc[i][j2], 0, 0, 0);
                }
        }

#pragma unroll
        for (int i = 0; i < 4; ++i)
#pragma unroll
            for (int r = 0; r < 4; ++r) {
                const int row = wr * 64 + i * 16 + fq * 4 + r;
                const float cv = CEN[row], cc = C0S[row];
                float al = 0.f;
#pragma unroll
                for (int j2 = 0; j2 < 2; ++j2) {
                    const int col = wc * 32 + j2 * 16 + fr;
                    const float dd = (float)(j0 + col) - cv;
                    const float s  = acc[i][j2][r] * 0.125f - cc * dd * dd;
                    al += __expf(s - M0_SHIFT);
                }
                lsum[i][r] += al;
            }
    }

    // reduce over fr lanes (bits 0..3), store per-wc partials
#pragma unroll
    for (int i = 0; i < 4; ++i)
#pragma unroll
        for (int r = 0; r < 4; ++r) {
            float v = lsum[i][r];
            v += __shfl_xor(v, 1);
            v += __shfl_xor(v, 2);
            v += __shfl_xor(v, 4);
            v += __shfl_xor(v, 8);
            if (fr == 0) LSUM[wc][wr * 64 + i * 16 + fq * 4 + r] = v;
        }
    __syncthreads();
    if (t < 128) RINV[t] = 1.f / (LSUM[0][t] + LSUM[1][t]);

    // ---------------- PASS B: attn write + PV ----------------
    f32v4 acco[4][2];
#pragma unroll
    for (int i = 0; i < 4; ++i)
#pragma unroll
        for (int j = 0; j < 2; ++j) acco[i][j] = zero;

    float* attnZ = attn + (size_t)z * 1024 * 1024;
    const unsigned short* vhb = vTh + (size_t)z * 64 * 1024;
    const unsigned short* vlb = vTl + (size_t)z * 64 * 1024;

    for (int jt = 0; jt < 16; ++jt) {
        const int j0 = jt * 64;
        __syncthreads();   // prev PV reads done; RINV visible on first iter
#pragma unroll
        for (int pp = 0; pp < 2; ++pp) {
            const int c   = t + pp * 256;
            const int row = c >> 3;
            const int seg = c & 7;
            const size_t ga = (size_t)(bq * 1024 + j0 + row) * 1024 + hd * 64 + seg * 8;
            const int sl = (seg ^ (row & 7)) * 8;
            *(u16v8*)&KH[row][sl] = *(const u16v8*)&kh[ga];
            *(u16v8*)&KL[row][sl] = *(const u16v8*)&kl[ga];
            const size_t va = (size_t)row * 1024 + j0 + seg * 8;
            *(u16v8*)&VH[row][sl] = *(const u16v8*)&vhb[va];
            *(u16v8*)&VL[row][sl] = *(const u16v8*)&vlb[va];
        }
        __syncthreads();

        f32v4 acc[4][2];
#pragma unroll
        for (int i = 0; i < 4; ++i)
#pragma unroll
            for (int j2 = 0; j2 < 2; ++j2) acc[i][j2] = zero;

#pragma unroll
        for (int kk = 0; kk < 2; ++kk) {
            bf16v8 fbh[2], fbl[2];
#pragma unroll
            for (int j2 = 0; j2 < 2; ++j2) {
                const int rb = wc * 32 + j2 * 16 + fr;
                const int sb = ((kk * 4 + fq) ^ (rb & 7)) * 8;
                fbh[j2] = *(const bf16v8*)&KH[rb][sb];
                fbl[j2] = *(const bf16v8*)&KL[rb][sb];
            }
#pragma unroll
            for (int i = 0; i < 4; ++i)
#pragma unroll
                for (int j2 = 0; j2 < 2; ++j2) {
                    acc[i][j2] = __builtin_amdgcn_mfma_f32_16x16x32_bf16(
                        qfh_[i][kk], fbh[j2], acc[i][j2], 0, 0, 0);
                    acc[i][j2] = __builtin_amdgcn_mfma_f32_16x16x32_bf16(
                        qfh_[i][kk], fbl[j2], acc[i][j2], 0, 0, 0);
                    acc[i][j2] = __builtin_amdgcn_mfma_f32_16x16x32_bf16(
                        qfl_[i][kk], fbh[j2], acc[i][j2], 0, 0, 0);
                }
        }

        // P = exp(s-8)*rinv: write attn f32 + scatter bf16 hi/lo to LDS
#pragma unroll
        for (int i = 0; i < 4; ++i)
#pragma unroll
            for (int r = 0; r < 4; ++r) {
                const int row = wr * 64 + i * 16 + fq * 4 + r;
                const float cv = CEN[row], cc = C0S[row], ri = RINV[row];
#pragma unroll
                for (int j2 = 0; j2 < 2; ++j2) {
                    const int col = wc * 32 + j2 * 16 + fr;
                    const float dd = (float)(j0 + col) - cv;
                    const float s  = acc[i][j2][r] * 0.125f - cc * dd * dd;
                    const float p  = __expf(s - M0_SHIFT) * ri;
                    attnZ[(size_t)(i0 + row) * 1024 + j0 + col] = p;
                    unsigned short hv, lv;
                    split2(p, hv, lv);
                    const int slot = ((col >> 3) ^ (row & 7)) * 8 + (col & 7);
                    PH[row][slot] = hv;
                    PL[row][slot] = lv;
                }
            }
        __syncthreads();

        // PV MFMA: out[128 q][64 d] += P[128][64] @ Vt[64 d][64 j]^T
#pragma unroll
        for (int kk = 0; kk < 2; ++kk) {
            bf16v8 pah[4], pal[4], fbh[2], fbl[2];
#pragma unroll
            for (int iq = 0; iq < 4; ++iq) {
                const int rp = wr * 64 + iq * 16 + fr;
                const int sp = ((kk * 4 + fq) ^ (rp & 7)) * 8;
                pah[iq] = *(const bf16v8*)&PH[rp][sp];
                pal[iq] = *(const bf16v8*)&PL[rp][sp];
            }
#pragma unroll
            for (int jd = 0; jd < 2; ++jd) {
                const int rb = wc * 32 + jd * 16 + fr;
                const int sb = ((kk * 4 + fq) ^ (rb & 7)) * 8;
                fbh[jd] = *(const bf16v8*)&VH[rb][sb];
                fbl[jd] = *(const bf16v8*)&VL[rb][sb];
            }
#pragma unroll
            for (int iq = 0; iq < 4; ++iq)
#pragma unroll
                for (int jd = 0; jd < 2; ++jd) {
                    acco[iq][jd] = __builtin_amdgcn_mfma_f32_16x16x32_bf16(
                        pah[iq], fbh[jd], acco[iq][jd], 0, 0, 0);
                    acco[iq][jd] = __builtin_amdgcn_mfma_f32_16x16x32_bf16(
                        pah[iq], fbl[jd], acco[iq][jd], 0, 0, 0);
                    acco[iq][jd] = __builtin_amdgcn_mfma_f32_16x16x32_bf16(
                        pal[iq], fbh[jd], acco[iq][jd], 0, 0, 0);
                }
        }
    }

    // epilogue: o row-major [4096][1024], col = h*64 + d, bf16 hi/lo
#pragma unroll
    for (int jd = 0; jd < 2; ++jd) {
        const int dcol = wc * 32 + jd * 16 + fr;
#pragma unroll
        for (int iq = 0; iq < 4; ++iq) {
            const int row0 = i0 + wr * 64 + iq * 16 + fq * 4;
            const f32v4 cv = acco[iq][jd];
#pragma unroll
            for (int r = 0; r < 4; ++r) {
                unsigned short hv, lv;
                split2(cv[r], hv, lv);
                const size_t idx = (size_t)(bq * 1024 + row0 + r) * 1024 + hd * 64 + dcol;
                oh[idx] = hv;
                ol[idx] = lv;
            }
        }
    }
}

// ---------------------------------------------------------------------------
extern "C" void kernel_launch(void* const* d_in, const int* in_sizes, int n_in,
                              void* d_out, int out_size, void* d_ws, size_t ws_size,
                              hipStream_t stream)
{
    const float* query = (const float*)d_in[0];
    const float* key_  = (const float*)d_in[1];
    const float* value = (const float*)d_in[2];
    const float* Wq  = (const float*)d_in[3];
    const float* bq  = (const float*)d_in[4];
    const float* Wk  = (const float*)d_in[5];
    const float* bk  = (const float*)d_in[6];
    const float* Wv  = (const float*)d_in[7];
    const float* bv  = (const float*)d_in[8];
    const float* Wp  = (const float*)d_in[9];
    const float* bp  = (const float*)d_in[10];
    const float* Wup = (const float*)d_in[11];
    const float* bup = (const float*)d_in[12];
    const float* Wud = (const float*)d_in[13];
    const float* bud = (const float*)d_in[14];
    const float* Wus = (const float*)d_in[15];
    const float* bus = (const float*)d_in[16];
    const float* Wo  = (const float*)d_in[17];
    const float* bo  = (const float*)d_in[18];

    float* x_out = (float*)d_out;                         // [4096,1024]
    float* attn  = x_out + (size_t)MTOT * HIDN;           // [64,1024,1024]

    // ---- workspace layout (bytes)
    char* wsb = (char*)d_ws;
    unsigned short* qh  = (unsigned short*)(wsb);                  // 8 MB
    unsigned short* ql  = (unsigned short*)(wsb + (8u  << 20));
    unsigned short* kh  = (unsigned short*)(wsb + (16u << 20));
    unsigned short* kl  = (unsigned short*)(wsb + (24u << 20));
    unsigned short* vTh = (unsigned short*)(wsb + (32u << 20));
    unsigned short* vTl = (unsigned short*)(wsb + (40u << 20));
    float* p_ws  = (float*)(wsb + (48u << 20));                    // 16 MB
    unsigned short* oh = (unsigned short*)(wsb + (48u << 20));     // overlays p
    unsigned short* ol = (unsigned short*)(wsb + (56u << 20));
    float* alpha_ws = (float*)(wsb + (64u << 20));                 // 256 KB
    float* cen_ws   = (float*)(wsb + (64u << 20) + (256u << 10));
    float* c0_ws    = (float*)(wsb + (64u << 20) + (512u << 10));
    // stage-1 split scratch lives in the (not-yet-written) attn region
    unsigned short* ah = (unsigned short*)attn;                    // 8 MB
    unsigned short* al = ah + (size_t)MTOT * HIDN;                 // 8 MB
    unsigned short* wh = al + (size_t)MTOT * HIDN;                 // 2 MB
    unsigned short* wl = wh + (size_t)HIDN * HIDN;                 // 2 MB
    // Wo split reuses qh/ql space after attn_fused
    unsigned short* w2h = qh;
    unsigned short* w2l = ql;

    const dim3 blk(256);
    const dim3 gsplit_a(MTOT * HIDN / 8 / 256);
    const dim3 gsplit_w(16, 16);
    const dim3 ggemm(HIDN / 128, MTOT / 128);

    // q = query @ Wq + bq -> qh/ql (bf16 only)
    split_w<<<gsplit_w, blk, 0, stream>>>(Wq, wh, wl);
    split_a<<<gsplit_a, blk, 0, stream>>>(query, ah, al);
    gemm_bf16x3<<<ggemm, blk, 0, stream>>>(ah, al, wh, wl, bq, nullptr, qh, ql, 0);
    // k -> kh/kl
    split_w<<<gsplit_w, blk, 0, stream>>>(Wk, wh, wl);
    split_a<<<gsplit_a, blk, 0, stream>>>(key_, ah, al);
    gemm_bf16x3<<<ggemm, blk, 0, stream>>>(ah, al, wh, wl, bk, nullptr, kh, kl, 0);
    // v -> vTh/vTl (per-head transposed)
    split_w<<<gsplit_w, blk, 0, stream>>>(Wv, wh, wl);
    split_a<<<gsplit_a, blk, 0, stream>>>(value, ah, al);
    gemm_bf16x3<<<ggemm, blk, 0, stream>>>(ah, al, wh, wl, bv, nullptr, vTh, vTl, 1);
    // p = q @ Wp + bp -> p_ws (f32); A is already-split qh/ql
    split_w<<<gsplit_w, blk, 0, stream>>>(Wp, wh, wl);
    gemm_bf16x3<<<ggemm, blk, 0, stream>>>(qh, ql, wh, wl, bp, p_ws, nullptr, nullptr, 0);
    // alpha + window params
    alpha_kernel<<<dim3(MTOT / 16), blk, 0, stream>>>(query, Wus, bus, alpha_ws);
    posparam_kernel<<<dim3((BATCH * NHEAD * S_LEN) / 256), blk, 0, stream>>>(
        p_ws, alpha_ws, Wup, bup, Wud, bud, cen_ws, c0_ws);
    // fused scores + softmax + attn-write + PV
    attn_fused<<<dim3(512), blk, 0, stream>>>(
        qh, ql, kh, kl, vTh, vTl, cen_ws, c0_ws, attn, oh, ol);
    // x = o @ Wo + bo
    split_w<<<gsplit_w, blk, 0, stream>>>(Wo, w2h, w2l);
    gemm_bf16x3<<<ggemm, blk, 0, stream>>>(oh, ol, w2h, w2l, bo, x_out,
                                           nullptr, nullptr, 0);
}